// Round 14
// baseline (288.914 us; speedup 1.0000x reference)
//
#include <hip/hip_runtime.h>
#include <hip/hip_bf16.h>
#include <math.h>

#define T 6
#define N 512
#define E 16384
#define EN (E + N)      // 16896 with self loops
#define H 8
#define D 128
#define HD 16
#define S (T * N)       // 3072
#define FIN 15
#define FF 2048
#define KS 4            // attention key-split
#define FCH 8           // FFN ff-chunk count (256 ff rows each)
#define GCH 64          // GAT edge chunk
#define NB (S/64)       // ffn_reduce blocks == pool partials (48)
#define SM_SHIFT2 2.88539008f   // static softmax shift, log2 domain
#define QSCALE 0.36067376f      // 0.25 * log2(e)
#define VPAD2 136       // V LDS row stride in halfs

typedef _Float16 half_t;
typedef _Float16 half8 __attribute__((ext_vector_type(8)));
typedef _Float16 half4 __attribute__((ext_vector_type(4)));
typedef float f32x4 __attribute__((ext_vector_type(4)));

#define MFMA16(a, b, c) __builtin_amdgcn_mfma_f32_16x16x32_f16(a, b, c, 0, 0, 0)
#define MFMA16K16(a, b, c) __builtin_amdgcn_mfma_f32_16x16x16f16(a, b, c, 0, 0, 0)

// ---------------- workspace layout (floats) ----------------
#define O_A      0
#define O_EBUF   (T*N*H*D)
#define O_C      (O_EBUF + T*EN*H)         // attn partials / ffn ypart
#define O_HSEQ   (O_C + T*N*H*D)
#define O_OBUF   (O_HSEQ + S*D)
#define O_SSRC   (O_OBUF + S*D)
#define O_SDST   (O_SSRC + T*N*H)
#define O_INT    (O_SDST + T*N*H)
#define O_G      (O_INT + 20000)           // gpart[NB][128]
#define O_CNT    (O_G + NB*128)            // completion counter (int)

// int-area offsets (ints, relative to O_INT)
#define I_START  0                         // [N+1]
#define I_CSRE   513                       // [EN]

// f16 weight area: inside O_A after Qh/Kh/Vt f16
#define WB_OFF   (3*H*S*HD)
#define WB_QKV   0
#define WB_WO    147456
#define WB_W1    196608
#define WB_W2    983040

__device__ __forceinline__ float bsum(float v, float* lds, int nw) {
    #pragma unroll
    for (int off = 32; off > 0; off >>= 1) v += __shfl_down(v, off, 64);
    int w = threadIdx.x >> 6;
    if ((threadIdx.x & 63) == 0) lds[w] = v;
    __syncthreads();
    float r = 0.f;
    for (int i = 0; i < nw; ++i) r += lds[i];
    __syncthreads();
    return r;
}

// swizzled pointer into a [rows][128] f16 LDS tile (row stride 256 B)
__device__ __forceinline__ half_t* swz_ptr(half_t* base, int token, int col) {
    int byte = token * 256 + col * 2;
    byte ^= (token & 7) << 4;
    return (half_t*)((char*)base + byte);
}
// swizzled pointer into a [rows][256] f16 LDS tile (row stride 512 B)
__device__ __forceinline__ half_t* swz_ptr256(half_t* base, int token, int col) {
    int byte = token * 512 + col * 2;
    byte ^= (token & 7) << 4;
    return (half_t*)((char*)base + byte);
}

// ---------------- GAT: lin + scores; block 0 also builds CSR and zeroes counter ----------------
__global__ __launch_bounds__(256) void gat_lin_kernel(
        const float* __restrict__ x, const float* __restrict__ W,
        const float* __restrict__ asrc, const float* __restrict__ adst,
        const int* __restrict__ ei, int* __restrict__ ia, int* __restrict__ cnt,
        half_t* __restrict__ hbuf16, float* __restrict__ ssrc, float* __restrict__ sdst) {
    int r = blockIdx.x;
    int tid = threadIdx.x;           // 256
    __shared__ float xr[FIN];
    __shared__ float hl[H*D];        // 4 KB
    if (tid < FIN) xr[tid] = x[r * FIN + tid];
    __syncthreads();
    #pragma unroll
    for (int kk = 0; kk < 4; ++kk) {
        int col = tid + kk * 256;
        float acc = 0.f;
        #pragma unroll
        for (int f = 0; f < FIN; ++f) acc += xr[f] * W[f * (H*D) + col];
        hbuf16[(size_t)r * (H*D) + col] = (half_t)acc;
        hl[col] = acc;
    }
    __syncthreads();
    int w = tid >> 6, lane = tid & 63;
    #pragma unroll
    for (int i = 0; i < 4; ++i) {
        int p = w*4 + i;
        int head = p >> 1;
        const float* av = ((p & 1) ? adst : asrc) + head * D;
        float v = hl[head*D + lane] * av[lane] + hl[head*D + 64 + lane] * av[64 + lane];
        #pragma unroll
        for (int off = 32; off > 0; off >>= 1) v += __shfl_down(v, off, 64);
        if (lane == 0) {
            if (p & 1) sdst[r*H + head] = v;
            else       ssrc[r*H + head] = v;
        }
    }

    // ---- block 0: CSR build (count + scan + fill) with 256 threads ----
    if (r == 0) {
        __shared__ int deg[N];       // reuses budget after hl no longer needed? keep separate (2KB+2KB)
        __shared__ int sbuf[N];
        if (tid == 0) *cnt = 0;      // zero pool completion counter (replay-safe)
        deg[tid] = 0; deg[tid + 256] = 0;
        __syncthreads();
        for (int j = tid; j < EN; j += 256) {
            int dn = (j < E) ? ei[E + j] : (j - E);
            atomicAdd(&deg[dn], 1);
        }
        __syncthreads();
        int v0 = deg[tid], v1 = deg[tid + 256];
        sbuf[tid] = v0; sbuf[tid + 256] = v1;
        __syncthreads();
        for (int off = 1; off < N; off <<= 1) {
            int i0 = tid, i1 = tid + 256;
            int a0 = (i0 >= off) ? sbuf[i0 - off] : 0;
            int a1 = (i1 >= off) ? sbuf[i1 - off] : 0;
            __syncthreads();
            sbuf[i0] += a0; sbuf[i1] += a1;
            __syncthreads();
        }
        ia[I_START + tid + 1] = sbuf[tid];
        ia[I_START + tid + 257] = sbuf[tid + 256];
        if (tid == 0) ia[I_START] = 0;
        deg[tid] = sbuf[tid] - v0;             // exclusive cursors
        deg[tid + 256] = sbuf[tid + 256] - v1;
        __syncthreads();
        for (int j = tid; j < EN; j += 256) {
            int dn = (j < E) ? ei[E + j] : (j - E);
            int slot = atomicAdd(&deg[dn], 1);
            ia[I_CSRE + slot] = j;
        }
    }
}

// ---------------- GAT fused: edge softmax (online, chunked) + gather + head-mean + LN ----------------
__global__ __launch_bounds__(128) void gat_fused_kernel(
        const int* __restrict__ ei, const int* __restrict__ ia,
        const float* __restrict__ ssrc, const float* __restrict__ sdst,
        const half_t* __restrict__ hbuf16, const float* __restrict__ gb,
        const float* __restrict__ lng, const float* __restrict__ lnb,
        float* __restrict__ hseq) {
    int bid = blockIdx.x;
    int wg = (bid & 7) * (T*N/8) + (bid >> 3);   // XCD-contiguous node ranges
    int t = wg / N, n = wg % N;
    int tid = threadIdx.x;           // 128
    int myh = tid & 7;

    __shared__ int snarr[GCH];
    __shared__ float earr[GCH][H];
    __shared__ float red[128];
    __shared__ float sdl[H], mS[H], sS[H], scl[H];
    __shared__ float lnred[2];

    if (tid < H) {
        sdl[tid] = sdst[(t*N + n)*H + tid];
        mS[tid] = -3.0e38f;
        sS[tid] = 0.f;
    }
    float acc[H];
    #pragma unroll
    for (int h = 0; h < H; ++h) acc[h] = 0.f;
    int e0 = ia[I_START + n], e1 = ia[I_START + n + 1];
    __syncthreads();

    for (int c0 = e0; c0 < e1; c0 += GCH) {
        int cn = min(GCH, e1 - c0);
        if (tid < cn) {
            int j = ia[I_CSRE + c0 + tid];
            snarr[tid] = (j < E) ? ei[j] : (j - E);
        }
        __syncthreads();
        float lm = -3.0e38f;
        for (int w = tid; w < cn*H; w += 128) {
            int ce = w >> 3;
            float e = ssrc[(t*N + snarr[ce])*H + myh] + sdl[myh];
            e = (e > 0.f) ? e : 0.2f * e;
            earr[ce][myh] = e;
            lm = fmaxf(lm, e);
        }
        red[tid] = lm;
        __syncthreads();
        if (tid < H) {
            float cm = red[tid];
            #pragma unroll
            for (int k = 1; k < 16; ++k) cm = fmaxf(cm, red[tid + 8*k]);
            float mn = fmaxf(mS[tid], cm);
            scl[tid] = __expf(mS[tid] - mn);
            mS[tid] = mn;
        }
        __syncthreads();
        float ls = 0.f;
        float mh = mS[myh];
        for (int w = tid; w < cn*H; w += 128) {
            int ce = w >> 3;
            float p = __expf(earr[ce][myh] - mh);
            earr[ce][myh] = p;
            ls += p;
        }
        red[tid] = ls;
        __syncthreads();
        if (tid < H) {
            float cs = red[tid];
            #pragma unroll
            for (int k = 1; k < 16; ++k) cs += red[tid + 8*k];
            sS[tid] = sS[tid] * scl[tid] + cs;
        }
        #pragma unroll
        for (int h = 0; h < H; ++h) acc[h] *= scl[h];
        for (int ce = 0; ce < cn; ++ce) {
            const half_t* hp = hbuf16 + ((size_t)(t*N + snarr[ce]) * H) * D + tid;
            #pragma unroll
            for (int h = 0; h < H; ++h)
                acc[h] += earr[ce][h] * (float)hp[(size_t)h * D];
        }
        __syncthreads();
    }

    float v = 0.f;
    #pragma unroll
    for (int h = 0; h < H; ++h) v += acc[h] / sS[h];
    v = v * (1.f / H) + gb[tid];
    float mean = bsum(v, lnred, 2) * (1.f / D);
    float diff = v - mean;
    float var = bsum(diff * diff, lnred, 2) * (1.f / D);
    hseq[(size_t)(t*N + n) * D + tid] = diff * rsqrtf(var + 1e-5f) * lng[tid] + lnb[tid];
}

// ---------------- weight transpose + f16 convert ----------------
__global__ __launch_bounds__(256) void wconv_kernel(
        const float* __restrict__ Wqkv, const float* __restrict__ Wo,
        const float* __restrict__ W1, const float* __restrict__ W2,
        half_t* __restrict__ WqkvT, half_t* __restrict__ WoT,
        half_t* __restrict__ W1T, half_t* __restrict__ W2T) {
    int b = blockIdx.x;              // 3 * 576
    int l = b / 576, r = b % 576;
    const float* src; half_t* dst; int Rr, Cc, tr, tc;
    if (r < 48)       { src = Wqkv + (size_t)l*128*384;  dst = WqkvT + (size_t)l*384*128;  Rr=128;  Cc=384;  tc = r % 12;        tr = r / 12; }
    else if (r < 64)  { int rr=r-48;  src = Wo + (size_t)l*128*128;  dst = WoT + (size_t)l*128*128;  Rr=128;  Cc=128;  tc = rr % 4;  tr = rr / 4; }
    else if (r < 320) { int rr=r-64;  src = W1 + (size_t)l*128*2048; dst = W1T + (size_t)l*2048*128; Rr=128;  Cc=2048; tc = rr % 64; tr = rr / 64; }
    else              { int rr=r-320; src = W2 + (size_t)l*2048*128; dst = W2T + (size_t)l*128*2048; Rr=2048; Cc=128;  tc = rr % 4;  tr = rr / 4; }
    __shared__ float t[32][33];
    int tx = threadIdx.x & 31, ty = threadIdx.x >> 5;
    #pragma unroll
    for (int i = 0; i < 4; ++i) {
        int row = tr*32 + ty + i*8, col = tc*32 + tx;
        t[ty + i*8][tx] = src[(size_t)row * Cc + col];
    }
    __syncthreads();
    #pragma unroll
    for (int i = 0; i < 4; ++i) {
        int orow = tc*32 + ty + i*8, ocol = tr*32 + tx;
        dst[(size_t)orow * Rr + ocol] = (half_t)t[tx][ty + i*8];
    }
}

// ---------------- QKV via MFMA (32 tokens/block); optionally fuses previous layer's
// FFN reduce + bias + residual + LN into the staging phase (doRed != 0) ----------------
__global__ __launch_bounds__(256) void qkv_mfma_kernel(
        float* __restrict__ hseq, const float* __restrict__ ypart,
        const float* __restrict__ b2, const float* __restrict__ lng2,
        const float* __restrict__ lnb2, int doRed,
        const half_t* __restrict__ WqkvT, const float* __restrict__ bqkv,
        half_t* __restrict__ Qh, half_t* __restrict__ Kh, half_t* __restrict__ Vt) {
    __shared__ half_t xt[32*128];
    int tid = threadIdx.x;
    int s0 = blockIdx.x * 32;
    if (doRed) {
        int token = tid >> 3, part = tid & 7;
        int s = s0 + token;
        const float* hres = hseq + (size_t)s * 128;
        float v[16];
        #pragma unroll
        for (int i = 0; i < 16; ++i) v[i] = b2[part*16 + i] + hres[part*16 + i];
        #pragma unroll
        for (int fcc = 0; fcc < FCH; ++fcc) {
            const float* yp = ypart + ((size_t)fcc*S + s)*128 + part*16;
            #pragma unroll
            for (int i = 0; i < 16; ++i) v[i] += yp[i];
        }
        float sum = 0.f;
        #pragma unroll
        for (int i = 0; i < 16; ++i) sum += v[i];
        sum += __shfl_xor(sum, 1, 64); sum += __shfl_xor(sum, 2, 64); sum += __shfl_xor(sum, 4, 64);
        float mean = sum * (1.f/128.f);
        float vs = 0.f;
        #pragma unroll
        for (int i = 0; i < 16; ++i) { float dq = v[i] - mean; vs += dq*dq; }
        vs += __shfl_xor(vs, 1, 64); vs += __shfl_xor(vs, 2, 64); vs += __shfl_xor(vs, 4, 64);
        float inv = rsqrtf(vs * (1.f/128.f) + 1e-5f);
        half8 o0, o1;
        #pragma unroll
        for (int i = 0; i < 16; ++i) {
            int dim = part*16 + i;
            float ov = (v[i]-mean)*inv*lng2[dim] + lnb2[dim];
            hseq[(size_t)s*128 + dim] = ov;
            if (i < 8) o0[i] = (half_t)ov; else o1[i-8] = (half_t)ov;
        }
        *(half8*)swz_ptr(xt, token, part*16) = o0;
        *(half8*)swz_ptr(xt, token, part*16 + 8) = o1;
    } else {
        for (int c = tid; c < 512; c += 256) {
            int token = c >> 4, col8 = (c & 15) * 8;
            const float* src = hseq + (size_t)(s0 + token) * 128 + col8;
            float4 a = *(const float4*)src;
            float4 b = *(const float4*)(src + 4);
            half8 v;
            v[0]=(half_t)a.x; v[1]=(half_t)a.y; v[2]=(half_t)a.z; v[3]=(half_t)a.w;
            v[4]=(half_t)b.x; v[5]=(half_t)b.y; v[6]=(half_t)b.z; v[7]=(half_t)b.w;
            *(half8*)swz_ptr(xt, token, col8) = v;
        }
    }
    __syncthreads();
    int lane = tid & 63, w = tid >> 6;
    int lr = lane & 15, lg = lane >> 4;
    f32x4 acc[6][2];
    #pragma unroll
    for (int m = 0; m < 6; ++m)
        #pragma unroll
        for (int n = 0; n < 2; ++n) acc[m][n] = (f32x4){0.f, 0.f, 0.f, 0.f};
    #pragma unroll
    for (int ks = 0; ks < 4; ++ks) {
        half8 bf[2];
        #pragma unroll
        for (int n = 0; n < 2; ++n)
            bf[n] = *(half8*)swz_ptr(xt, n*16 + lr, ks*32 + lg*8);
        #pragma unroll
        for (int m = 0; m < 6; ++m) {
            int row = w*96 + m*16 + lr;
            half8 af = *(const half8*)(WqkvT + (size_t)row*128 + ks*32 + lg*8);
            #pragma unroll
            for (int n = 0; n < 2; ++n) acc[m][n] = MFMA16(af, bf[n], acc[m][n]);
        }
    }
    #pragma unroll
    for (int m = 0; m < 6; ++m) {
        int qd = w*96 + m*16 + lg*4;
        float4 bb = *(const float4*)(bqkv + qd);
        int part = qd >> 7, c = qd & 127, head = c >> 4, dd = c & 15;
        #pragma unroll
        for (int n = 0; n < 2; ++n) {
            int token = n*16 + lr;
            float v0 = acc[m][n][0] + bb.x, v1 = acc[m][n][1] + bb.y;
            float v2 = acc[m][n][2] + bb.z, v3 = acc[m][n][3] + bb.w;
            if (part == 0) {
                half4 hv = { (half_t)(v0*QSCALE), (half_t)(v1*QSCALE),
                             (half_t)(v2*QSCALE), (half_t)(v3*QSCALE) };
                *(half4*)(Qh + ((size_t)head*S + s0 + token)*HD + dd) = hv;
            } else if (part == 1) {
                half4 hv = { (half_t)v0, (half_t)v1, (half_t)v2, (half_t)v3 };
                *(half4*)(Kh + ((size_t)head*S + s0 + token)*HD + dd) = hv;
            } else {
                Vt[((size_t)head*HD + dd + 0)*S + s0 + token] = (half_t)v0;
                Vt[((size_t)head*HD + dd + 1)*S + s0 + token] = (half_t)v1;
                Vt[((size_t)head*HD + dd + 2)*S + s0 + token] = (half_t)v2;
                Vt[((size_t)head*HD + dd + 3)*S + s0 + token] = (half_t)v3;
            }
        }
    }
}

// ---------------- Attention v7: 32 queries/wave (128/block), 128-key LDS tiles ----------------
__global__ __launch_bounds__(256) void attn7_kernel(
        const half_t* __restrict__ Qh, const half_t* __restrict__ Kh,
        const half_t* __restrict__ Vt, float* __restrict__ pacc,
        float* __restrict__ pl) {
    int qb = blockIdx.x, h = blockIdx.y, ks = blockIdx.z;
    int tid = threadIdx.x;
    int lane = tid & 63;
    int w = tid >> 6;
    int lr = lane & 15, lg = lane >> 4;
    int qg0 = qb*128 + w*32 + lr;
    int qg1 = qg0 + 16;
    const f32x4 zf = {0.f, 0.f, 0.f, 0.f};

    __shared__ half_t kbuf[2][128*16];
    __shared__ half_t vbuf[2][16*VPAD2];

    half4 qf0 = *(const half4*)(Qh + ((size_t)h*S + qg0)*HD + lg*4);
    half4 qf1 = *(const half4*)(Qh + ((size_t)h*S + qg1)*HD + lg*4);

    int krow = tid >> 1, kch = tid & 1;
    int vdim = tid >> 4, vch = tid & 15;
    const half_t* Kbase = Kh + (size_t)h*S*HD;
    const half_t* Vbase = Vt + (size_t)h*HD*S;
    int kb0 = ks*(S/KS);

    *(half8*)&kbuf[0][krow*16 + kch*8] = *(const half8*)(Kbase + (size_t)(kb0+krow)*HD + kch*8);
    *(half8*)&vbuf[0][vdim*VPAD2 + vch*8] = *(const half8*)(Vbase + (size_t)vdim*S + kb0 + vch*8);
    __syncthreads();

    float l0 = 0.f, l1 = 0.f;
    f32x4 oa0 = zf, oa1 = zf, ob0 = zf, ob1 = zf;
    int cur = 0;
    const int NT = (S/KS)/128;               // 6
    for (int t = 0; t < NT; ++t) {
        half8 knext, vnext;
        if (t+1 < NT) {
            int kbn = kb0 + (t+1)*128;
            knext = *(const half8*)(Kbase + (size_t)(kbn+krow)*HD + kch*8);
            vnext = *(const half8*)(Vbase + (size_t)vdim*S + kbn + vch*8);
        }

        f32x4 sc0[8], sc1[8];
        #pragma unroll
        for (int ct = 0; ct < 8; ++ct) {
            half4 kf = *(half4*)&kbuf[cur][(ct*16+lr)*16 + lg*4];
            sc0[ct] = MFMA16K16(kf, qf0, zf);
            sc1[ct] = MFMA16K16(kf, qf1, zf);
        }
        half4 pf0[8], pf1[8];
        #pragma unroll
        for (int ct = 0; ct < 8; ++ct)
            #pragma unroll
            for (int r = 0; r < 4; ++r) {
                float pv0 = exp2f(sc0[ct][r] - SM_SHIFT2);
                float pv1 = exp2f(sc1[ct][r] - SM_SHIFT2);
                l0 += pv0; l1 += pv1;
                pf0[ct][r] = (half_t)pv0;
                pf1[ct][r] = (half_t)pv1;
            }
        #pragma unroll
        for (int ct = 0; ct < 8; ++ct) {
            half4 vf = *(half4*)&vbuf[cur][lr*VPAD2 + ct*16 + lg*4];
            if (ct & 1) { oa1 = MFMA16K16(vf, pf0[ct], oa1); ob1 = MFMA16K16(vf, pf1[ct], ob1); }
            else        { oa0 = MFMA16K16(vf, pf0[ct], oa0); ob0 = MFMA16K16(vf, pf1[ct], ob0); }
        }
        if (t+1 < NT) {
            *(half8*)&kbuf[cur^1][krow*16 + kch*8] = knext;
            *(half8*)&vbuf[cur^1][vdim*VPAD2 + vch*8] = vnext;
            __syncthreads();
            cur ^= 1;
        }
    }
    oa0[0]+=oa1[0]; oa0[1]+=oa1[1]; oa0[2]+=oa1[2]; oa0[3]+=oa1[3];
    ob0[0]+=ob1[0]; ob0[1]+=ob1[1]; ob0[2]+=ob1[2]; ob0[3]+=ob1[3];

    l0 += __shfl_xor(l0, 16, 64); l0 += __shfl_xor(l0, 32, 64);
    l1 += __shfl_xor(l1, 16, 64); l1 += __shfl_xor(l1, 32, 64);

    size_t oi0 = ((size_t)(ks*H + h) * S + qg0);
    size_t oi1 = ((size_t)(ks*H + h) * S + qg1);
    if (lg == 0) { pl[oi0] = l0; pl[oi1] = l1; }
    #pragma unroll
    for (int r = 0; r < 4; ++r) {
        pacc[oi0 * HD + lg*4 + r] = oa0[r];
        pacc[oi1 * HD + lg*4 + r] = ob0[r];
    }
}

// ---------------- out-proj + residual + LN via MFMA (32 tokens/block), attn-combine fused ----------------
__global__ __launch_bounds__(256) void oproj_mfma_ln_kernel(
        const float* __restrict__ pacc, const float* __restrict__ pl,
        const half_t* __restrict__ WoT,
        const float* __restrict__ bo, const float* __restrict__ lng,
        const float* __restrict__ lnb, float* __restrict__ hseq) {
    __shared__ half_t xt[32*128];
    __shared__ float yt[32*132];
    int tid = threadIdx.x;
    int s0 = blockIdx.x * 32;
    for (int c = tid; c < 512; c += 256) {
        int token = c >> 4, col8 = (c & 15) * 8;
        int s = s0 + token;
        int h = col8 >> 4, dd0 = col8 & 15;
        float L = 0.f;
        float a[8] = {0,0,0,0,0,0,0,0};
        #pragma unroll
        for (int k = 0; k < KS; ++k) {
            size_t oi = ((size_t)(k*H + h) * S + s);
            L += pl[oi];
            const float* pp = pacc + oi * HD + dd0;
            float4 p0 = *(const float4*)pp;
            float4 p1 = *(const float4*)(pp + 4);
            a[0]+=p0.x; a[1]+=p0.y; a[2]+=p0.z; a[3]+=p0.w;
            a[4]+=p1.x; a[5]+=p1.y; a[6]+=p1.z; a[7]+=p1.w;
        }
        float inv = 1.f / L;
        half8 v;
        #pragma unroll
        for (int i = 0; i < 8; ++i) v[i] = (half_t)(a[i] * inv);
        *(half8*)swz_ptr(xt, token, col8) = v;
    }
    __syncthreads();
    int lane = tid & 63, w = tid >> 6;
    int lr = lane & 15, lg = lane >> 4;
    f32x4 acc[2][2];
    #pragma unroll
    for (int m = 0; m < 2; ++m)
        #pragma unroll
        for (int n = 0; n < 2; ++n) acc[m][n] = (f32x4){0.f, 0.f, 0.f, 0.f};
    #pragma unroll
    for (int kk = 0; kk < 4; ++kk) {
        half8 bf[2];
        #pragma unroll
        for (int n = 0; n < 2; ++n)
            bf[n] = *(half8*)swz_ptr(xt, n*16 + lr, kk*32 + lg*8);
        #pragma unroll
        for (int m = 0; m < 2; ++m) {
            int row = w*32 + m*16 + lr;
            half8 af = *(const half8*)(WoT + (size_t)row*128 + kk*32 + lg*8);
            #pragma unroll
            for (int n = 0; n < 2; ++n) acc[m][n] = MFMA16(af, bf[n], acc[m][n]);
        }
    }
    #pragma unroll
    for (int m = 0; m < 2; ++m)
        #pragma unroll
        for (int n = 0; n < 2; ++n) {
            int token = n*16 + lr;
            int od = w*32 + m*16 + lg*4;
            *(f32x4*)&yt[token*132 + od] = acc[m][n];
        }
    __syncthreads();
    {
        int token = tid >> 3, part = tid & 7;
        const float* hres = hseq + (size_t)(s0 + token) * 128;
        float v[16];
        float sum = 0.f;
        #pragma unroll
        for (int i = 0; i < 16; ++i) {
            int dim = part*16 + i;
            v[i] = yt[token*132 + dim] + bo[dim] + hres[dim];
            sum += v[i];
        }
        sum += __shfl_xor(sum, 1, 64); sum += __shfl_xor(sum, 2, 64); sum += __shfl_xor(sum, 4, 64);
        float mean = sum * (1.f/128.f);
        float vs = 0.f;
        #pragma unroll
        for (int i = 0; i < 16; ++i) { float dq = v[i] - mean; vs += dq*dq; }
        vs += __shfl_xor(vs, 1, 64); vs += __shfl_xor(vs, 2, 64); vs += __shfl_xor(vs, 4, 64);
        float inv = rsqrtf(vs * (1.f/128.f) + 1e-5f);
        #pragma unroll
        for (int i = 0; i < 16; ++i) {
            int dim = part*16 + i;
            hseq[(size_t)(s0+token)*128 + dim] = (v[i]-mean)*inv*lng[dim] + lnb[dim];
        }
    }
}

// ---------------- FFN split-FF: grid (96, FCH) -> partial Y into ypart ----------------
__global__ __launch_bounds__(256) void ffn_mfma2_kernel(
        const half_t* __restrict__ W1T, const half_t* __restrict__ W2T,
        const float* __restrict__ b1, const float* __restrict__ hseq,
        float* __restrict__ ypart) {
    __shared__ half_t xt[32*128];      // 8 KB
    __shared__ half_t h1[32*256];      // 16 KB
    int tid = threadIdx.x;             // 256
    int s0 = blockIdx.x * 32;
    int fc = blockIdx.y;
    int fbase = fc * 256;
    for (int c = tid; c < 512; c += 256) {
        int token = c >> 4, col8 = (c & 15) * 8;
        const float* src = hseq + (size_t)(s0 + token) * 128 + col8;
        float4 a = *(const float4*)src;
        float4 b = *(const float4*)(src + 4);
        half8 v;
        v[0]=(half_t)a.x; v[1]=(half_t)a.y; v[2]=(half_t)a.z; v[3]=(half_t)a.w;
        v[4]=(half_t)b.x; v[5]=(half_t)b.y; v[6]=(half_t)b.z; v[7]=(half_t)b.w;
        *(half8*)swz_ptr(xt, token, col8) = v;
    }
    __syncthreads();
    int lane = tid & 63, mw = tid >> 6;
    int lr = lane & 15, lg = lane >> 4;

    f32x4 hacc[4][2];
    #pragma unroll
    for (int m = 0; m < 4; ++m)
        #pragma unroll
        for (int n = 0; n < 2; ++n) hacc[m][n] = (f32x4){0.f, 0.f, 0.f, 0.f};
    #pragma unroll
    for (int ksx = 0; ksx < 4; ++ksx) {
        half8 bf[2];
        #pragma unroll
        for (int n = 0; n < 2; ++n)
            bf[n] = *(half8*)swz_ptr(xt, n*16 + lr, ksx*32 + lg*8);
        #pragma unroll
        for (int m = 0; m < 4; ++m) {
            int row = fbase + mw*64 + m*16 + lr;
            half8 af = *(const half8*)(W1T + (size_t)row*128 + ksx*32 + lg*8);
            #pragma unroll
            for (int n = 0; n < 2; ++n) hacc[m][n] = MFMA16(af, bf[n], hacc[m][n]);
        }
    }
    #pragma unroll
    for (int m = 0; m < 4; ++m) {
        int frow = mw*64 + m*16 + lg*4;
        float4 bb = *(const float4*)(b1 + fbase + frow);
        #pragma unroll
        for (int n = 0; n < 2; ++n) {
            int token = n*16 + lr;
            half4 hv;
            hv[0] = (half_t)fmaxf(hacc[m][n][0] + bb.x, 0.f);
            hv[1] = (half_t)fmaxf(hacc[m][n][1] + bb.y, 0.f);
            hv[2] = (half_t)fmaxf(hacc[m][n][2] + bb.z, 0.f);
            hv[3] = (half_t)fmaxf(hacc[m][n][3] + bb.w, 0.f);
            *(half4*)swz_ptr256(h1, token, frow) = hv;
        }
    }
    __syncthreads();

    f32x4 yacc[2][2];
    #pragma unroll
    for (int m = 0; m < 2; ++m)
        #pragma unroll
        for (int n = 0; n < 2; ++n) yacc[m][n] = (f32x4){0.f, 0.f, 0.f, 0.f};
    #pragma unroll
    for (int ksx = 0; ksx < 8; ++ksx) {
        half8 bf[2];
        #pragma unroll
        for (int n = 0; n < 2; ++n)
            bf[n] = *(half8*)swz_ptr256(h1, n*16 + lr, ksx*32 + lg*8);
        #pragma unroll
        for (int m = 0; m < 2; ++m) {
            int row = mw*32 + m*16 + lr;
            half8 af = *(const half8*)(W2T + (size_t)row*2048 + fbase + ksx*32 + lg*8);
            #pragma unroll
            for (int n = 0; n < 2; ++n) yacc[m][n] = MFMA16(af, bf[n], yacc[m][n]);
        }
    }
    #pragma unroll
    for (int m = 0; m < 2; ++m)
        #pragma unroll
        for (int n = 0; n < 2; ++n) {
            int token = n*16 + lr;
            int od = mw*32 + m*16 + lg*4;
            *(f32x4*)&ypart[((size_t)fc*S + s0 + token)*128 + od] = yacc[m][n];
        }
}

// ---------------- FFN reduce + LN + pool partials + (last block) heads ----------------
__global__ __launch_bounds__(256) void ffn_reduce_ln_pool_kernel(
        const float* __restrict__ ypart, const float* __restrict__ b2,
        const float* __restrict__ lng, const float* __restrict__ lnb,
        float* __restrict__ hseq, float* __restrict__ gpart, int* __restrict__ cnt,
        const float* __restrict__ rW1, const float* __restrict__ rb1,
        const float* __restrict__ rW2, const float* __restrict__ rb2,
        const float* __restrict__ mW1, const float* __restrict__ mb1,
        const float* __restrict__ mW2, const float* __restrict__ mb2,
        const float* __restrict__ uW1, const float* __restrict__ ub1,
        const float* __restrict__ uW2, const float* __restrict__ ub2,
        float* __restrict__ out) {
    __shared__ float wsum[4][128];
    __shared__ int isLast;
    int tid = threadIdx.x;             // 256: 64 tokens x 4 parts
    int token = blockIdx.x * 64 + (tid >> 2);
    int part = tid & 3;                // 32 dims each
    int lane = tid & 63, wv = tid >> 6;
    const float* hres = hseq + (size_t)token * 128;
    float v[32];
    #pragma unroll
    for (int i = 0; i < 32; ++i) {
        int dim = part*32 + i;
        v[i] = b2[dim] + hres[dim];
    }
    #pragma unroll
    for (int fcc = 0; fcc < FCH; ++fcc) {
        const float* yp = ypart + ((size_t)fcc*S + token)*128 + part*32;
        #pragma unroll
        for (int i = 0; i < 32; ++i) v[i] += yp[i];
    }
    float sum = 0.f;
    #pragma unroll
    for (int i = 0; i < 32; ++i) sum += v[i];
    sum += __shfl_xor(sum, 1, 64); sum += __shfl_xor(sum, 2, 64);
    float mean = sum * (1.f/128.f);
    float vs = 0.f;
    #pragma unroll
    for (int i = 0; i < 32; ++i) { float dq = v[i] - mean; vs += dq*dq; }
    vs += __shfl_xor(vs, 1, 64); vs += __shfl_xor(vs, 2, 64);
    float inv = rsqrtf(vs * (1.f/128.f) + 1e-5f);
    float o[32];
    #pragma unroll
    for (int i = 0; i < 32; ++i) {
        int dim = part*32 + i;
        o[i] = (v[i]-mean)*inv*lng[dim] + lnb[dim];
        hseq[(size_t)token*128 + dim] = o[i];
    }
    // pool partial: sum o[] across the 16 tokens of this wave
    #pragma unroll
    for (int i = 0; i < 32; ++i) {
        o[i] += __shfl_xor(o[i], 4, 64);
        o[i] += __shfl_xor(o[i], 8, 64);
        o[i] += __shfl_xor(o[i], 16, 64);
        o[i] += __shfl_xor(o[i], 32, 64);
    }
    if (lane < 4) {
        #pragma unroll
        for (int i = 0; i < 32; ++i) wsum[wv][lane*32 + i] = o[i];
    }
    __syncthreads();
    if (tid < 128)
        gpart[(size_t)blockIdx.x * 128 + tid] =
            wsum[0][tid] + wsum[1][tid] + wsum[2][tid] + wsum[3][tid];

    // ---- completion: last block computes the heads ----
    __threadfence();
    __syncthreads();
    if (tid == 0) isLast = (atomicAdd(cnt, 1) == NB - 1);
    __syncthreads();
    if (!isLast) return;
    __threadfence();                 // acquire: see all gpart writes
    if (tid == 0) *cnt = 0;          // reset for next graph replay

    __shared__ float gl[D];
    __shared__ float r1[64];
    __shared__ float mh[32];
    __shared__ float uh[32];
    if (tid < 128) {
        float acc = 0.f;
        for (int b = 0; b < NB; ++b) acc += gpart[(size_t)b * 128 + tid];
        gl[tid] = acc * (1.f / S);
    }
    __syncthreads();
    if (tid < 64) {
        float acc = rb1[tid];
        for (int k = 0; k < D; ++k) acc += gl[k] * rW1[k * 64 + tid];
        r1[tid] = fmaxf(acc, 0.f);
    }
    if (tid >= 64 && tid < 96) {
        int t = tid - 64;
        float am = mb1[t], au = ub1[t];
        for (int k = 0; k < D; ++k) {
            am += gl[k] * mW1[k * 32 + t];
            au += gl[k] * uW1[k * 32 + t];
        }
        mh[t] = fmaxf(am, 0.f);
        uh[t] = fmaxf(au, 0.f);
    }
    __syncthreads();
    if (tid == 0) {
        float acc = rb2[0];
        for (int k = 0; k < 64; ++k) acc += r1[k] * rW2[k];
        out[0] = 1.f / (1.f + __expf(-acc));
    }
    if (tid >= 8 && tid < 16) {
        int t = tid - 8;
        float acc = mb2[t];
        for (int k = 0; k < 32; ++k) acc += mh[k] * mW2[k * 8 + t];
        out[1 + t] = acc;
    }
    if (tid >= 16 && tid < 18) {
        int t = tid - 16;
        float acc = ub2[t];
        for (int k = 0; k < 32; ++k) acc += uh[k] * uW2[k * 2 + t];
        out[9 + t] = (acc > 20.f) ? acc : log1pf(__expf(acc));
    }
}

extern "C" void kernel_launch(void* const* d_in, const int* in_sizes, int n_in,
                              void* d_out, int out_size, void* d_ws, size_t ws_size,
                              hipStream_t stream) {
    const float* x       = (const float*)d_in[0];
    const int*   ei      = (const int*)  d_in[1];
    const float* gat_W   = (const float*)d_in[2];
    const float* gat_asrc= (const float*)d_in[3];
    const float* gat_adst= (const float*)d_in[4];
    const float* gat_b   = (const float*)d_in[5];
    const float* ln_g    = (const float*)d_in[6];
    const float* ln_b    = (const float*)d_in[7];
    const float* Wqkv    = (const float*)d_in[8];
    const float* bqkv    = (const float*)d_in[9];
    const float* Wo      = (const float*)d_in[10];
    const float* bo      = (const float*)d_in[11];
    const float* ln1g    = (const float*)d_in[12];
    const float* ln1b    = (const float*)d_in[13];
    const float* W1      = (const float*)d_in[14];
    const float* b1      = (const float*)d_in[15];
    const float* W2      = (const float*)d_in[16];
    const float* b2      = (const float*)d_in[17];
    const float* ln2g    = (const float*)d_in[18];
    const float* ln2b    = (const float*)d_in[19];
    const float* rW1     = (const float*)d_in[20];
    const float* rb1     = (const float*)d_in[21];
    const float* rW2     = (const float*)d_in[22];
    const float* rb2     = (const float*)d_in[23];
    const float* mW1     = (const float*)d_in[24];
    const float* mb1     = (const float*)d_in[25];
    const float* mW2     = (const float*)d_in[26];
    const float* mb2     = (const float*)d_in[27];
    const float* uW1     = (const float*)d_in[28];
    const float* ub1     = (const float*)d_in[29];
    const float* uW2     = (const float*)d_in[30];
    const float* ub2     = (const float*)d_in[31];

    float* ws = (float*)d_ws;
    half_t*       hbuf16 = (half_t*)(ws + O_A);
    half_t*       Qh   = (half_t*)(ws + O_A);
    half_t*       Kh   = Qh + (size_t)H*S*HD;
    half_t*       Vt   = Kh + (size_t)H*S*HD;
    half_t*       wb   = (half_t*)(ws + O_A + WB_OFF);
    half_t*       WqkvT= wb + WB_QKV;
    half_t*       WoT  = wb + WB_WO;
    half_t*       W1T  = wb + WB_W1;
    half_t*       W2T  = wb + WB_W2;
    float*        pacc = ws + O_C;
    float*        ypart= ws + O_C;
    float*        pl   = ws + O_C + (size_t)KS*H*S*HD;
    float*        hseq = ws + O_HSEQ;
    float*        ssrc = ws + O_SSRC;
    float*        sdst = ws + O_SDST;
    int*          ia   = (int*)(ws + O_INT);
    float*        gpart= ws + O_G;
    int*          cnt  = (int*)(ws + O_CNT);
    float* out = (float*)d_out;

    // ---- GAT (block 0 also builds CSR + zeroes counter) ----
    gat_lin_kernel<<<dim3(T*N), dim3(256), 0, stream>>>(x, gat_W, gat_asrc, gat_adst,
                                                        ei, ia, cnt, hbuf16, ssrc, sdst);
    gat_fused_kernel<<<dim3(T*N), dim3(128), 0, stream>>>(
        ei, ia, ssrc, sdst, hbuf16, gat_b, ln_g, ln_b, hseq);

    // ---- weight convert ----
    wconv_kernel<<<dim3(3*576), dim3(256), 0, stream>>>(Wqkv, Wo, W1, W2, WqkvT, WoT, W1T, W2T);

    // ---- transformer layers ----
    for (int l = 0; l < 3; ++l) {
        qkv_mfma_kernel<<<dim3(S/32), dim3(256), 0, stream>>>(
            hseq, ypart, b2 + (l-1)*D, ln2g + (l-1)*D, ln2b + (l-1)*D, (l > 0) ? 1 : 0,
            WqkvT + (size_t)l*384*128, bqkv + l*3*D, Qh, Kh, Vt);
        attn7_kernel<<<dim3(S/128, H, KS), dim3(256), 0, stream>>>(Qh, Kh, Vt, pacc, pl);
        oproj_mfma_ln_kernel<<<dim3(S/32), dim3(256), 0, stream>>>(
            pacc, pl, WoT + (size_t)l*128*128, bo + l*D, ln1g + l*D, ln1b + l*D, hseq);
        ffn_mfma2_kernel<<<dim3(S/32, FCH), dim3(256), 0, stream>>>(
            W1T + (size_t)l*2048*128, W2T + (size_t)l*128*2048,
            b1 + l*FF, hseq, ypart);
    }
    // last layer's FFN reduce + LN + pool partials + heads (fused, last-block)
    ffn_reduce_ln_pool_kernel<<<dim3(NB), dim3(256), 0, stream>>>(
        ypart, b2 + 2*D, ln2g + 2*D, ln2b + 2*D, hseq, gpart, cnt,
        rW1, rb1, rW2, rb2, mW1, mb1, mW2, mb2, uW1, ub1, uW2, ub2, out);
}

// Round 15
// 280.945 us; speedup vs baseline: 1.0284x; 1.0284x over previous
//
#include <hip/hip_runtime.h>
#include <hip/hip_bf16.h>
#include <math.h>

#define T 6
#define N 512
#define E 16384
#define EN (E + N)      // 16896 with self loops
#define H 8
#define D 128
#define HD 16
#define S (T * N)       // 3072
#define FIN 15
#define FF 2048
#define KS 4            // attention key-split
#define FCH 8           // FFN ff-chunk count (256 ff rows each)
#define GCH 64          // GAT edge chunk
#define NB (S/64)       // ffn_reduce blocks == pool partials (48)
#define SM_SHIFT2 2.88539008f   // static softmax shift, log2 domain
#define QSCALE 0.36067376f      // 0.25 * log2(e)
#define VPAD2 136       // V LDS row stride in halfs

typedef _Float16 half_t;
typedef _Float16 half8 __attribute__((ext_vector_type(8)));
typedef _Float16 half4 __attribute__((ext_vector_type(4)));
typedef float f32x4 __attribute__((ext_vector_type(4)));

#define MFMA16(a, b, c) __builtin_amdgcn_mfma_f32_16x16x32_f16(a, b, c, 0, 0, 0)
#define MFMA16K16(a, b, c) __builtin_amdgcn_mfma_f32_16x16x16f16(a, b, c, 0, 0, 0)

// ---------------- workspace layout (floats) ----------------
#define O_A      0
#define O_EBUF   (T*N*H*D)
#define O_C      (O_EBUF + T*EN*H)         // attn partials / ffn ypart
#define O_HSEQ   (O_C + T*N*H*D)
#define O_OBUF   (O_HSEQ + S*D)
#define O_SSRC   (O_OBUF + S*D)
#define O_SDST   (O_SSRC + T*N*H)
#define O_INT    (O_SDST + T*N*H)
#define O_G      (O_INT + 20000)           // gpart[NB][128]
#define O_CNT    (O_G + NB*128)            // completion counter (int)

// int-area offsets (ints, relative to O_INT)
#define I_START  0                         // [N+1]
#define I_CSRE   513                       // [EN]

// f16 weight area: inside O_A after Qh/Kh/Vt f16
#define WB_OFF   (3*H*S*HD)
#define WB_QKV   0
#define WB_WO    147456
#define WB_W1    196608
#define WB_W2    983040

__device__ __forceinline__ float bsum(float v, float* lds, int nw) {
    #pragma unroll
    for (int off = 32; off > 0; off >>= 1) v += __shfl_down(v, off, 64);
    int w = threadIdx.x >> 6;
    if ((threadIdx.x & 63) == 0) lds[w] = v;
    __syncthreads();
    float r = 0.f;
    for (int i = 0; i < nw; ++i) r += lds[i];
    __syncthreads();
    return r;
}

// swizzled pointer into a [rows][128] f16 LDS tile (row stride 256 B)
__device__ __forceinline__ half_t* swz_ptr(half_t* base, int token, int col) {
    int byte = token * 256 + col * 2;
    byte ^= (token & 7) << 4;
    return (half_t*)((char*)base + byte);
}
// swizzled pointer into a [rows][256] f16 LDS tile (row stride 512 B)
__device__ __forceinline__ half_t* swz_ptr256(half_t* base, int token, int col) {
    int byte = token * 512 + col * 2;
    byte ^= (token & 7) << 4;
    return (half_t*)((char*)base + byte);
}

// ---------------- GAT: lin + per-(t,n,head) src/dst scores fused ----------------
__global__ __launch_bounds__(256) void gat_lin_kernel(
        const float* __restrict__ x, const float* __restrict__ W,
        const float* __restrict__ asrc, const float* __restrict__ adst,
        half_t* __restrict__ hbuf16, float* __restrict__ ssrc, float* __restrict__ sdst) {
    int r = blockIdx.x;
    int tid = threadIdx.x;           // 256
    __shared__ float xr[FIN];
    __shared__ float hl[H*D];        // 4 KB
    if (tid < FIN) xr[tid] = x[r * FIN + tid];
    __syncthreads();
    #pragma unroll
    for (int kk = 0; kk < 4; ++kk) {
        int col = tid + kk * 256;
        float acc = 0.f;
        #pragma unroll
        for (int f = 0; f < FIN; ++f) acc += xr[f] * W[f * (H*D) + col];
        hbuf16[(size_t)r * (H*D) + col] = (half_t)acc;
        hl[col] = acc;
    }
    __syncthreads();
    int w = tid >> 6, lane = tid & 63;
    #pragma unroll
    for (int i = 0; i < 4; ++i) {
        int p = w*4 + i;
        int head = p >> 1;
        const float* av = ((p & 1) ? adst : asrc) + head * D;
        float v = hl[head*D + lane] * av[lane] + hl[head*D + 64 + lane] * av[64 + lane];
        #pragma unroll
        for (int off = 32; off > 0; off >>= 1) v += __shfl_down(v, off, 64);
        if (lane == 0) {
            if (p & 1) sdst[r*H + head] = v;
            else       ssrc[r*H + head] = v;
        }
    }
}

// ---------------- CSR build: count + scan + fill, one block, all in LDS; zeroes cnt ----------------
__global__ __launch_bounds__(512) void csr_build_kernel(const int* __restrict__ ei, int* ia,
                                                        int* __restrict__ cnt) {
    __shared__ int deg[N];           // degree, then reused as cursor
    __shared__ int buf[N];
    int tid = threadIdx.x;           // 512 == N
    if (tid == 0) *cnt = 0;          // zero pool completion counter (replay-safe)
    deg[tid] = 0;
    __syncthreads();
    for (int j = tid; j < EN; j += 512) {
        int dn = (j < E) ? ei[E + j] : (j - E);
        atomicAdd(&deg[dn], 1);
    }
    __syncthreads();
    int v = deg[tid];
    buf[tid] = v;
    __syncthreads();
    for (int off = 1; off < N; off <<= 1) {
        int t = (tid >= off) ? buf[tid - off] : 0;
        __syncthreads();
        buf[tid] += t;
        __syncthreads();
    }
    ia[I_START + tid + 1] = buf[tid];
    if (tid == 0) ia[I_START] = 0;
    deg[tid] = buf[tid] - v;         // exclusive cursor
    __syncthreads();
    for (int j = tid; j < EN; j += 512) {
        int dn = (j < E) ? ei[E + j] : (j - E);
        int slot = atomicAdd(&deg[dn], 1);
        ia[I_CSRE + slot] = j;
    }
}

// ---------------- GAT fused: edge softmax (online, chunked) + gather + head-mean + LN ----------------
__global__ __launch_bounds__(128) void gat_fused_kernel(
        const int* __restrict__ ei, const int* __restrict__ ia,
        const float* __restrict__ ssrc, const float* __restrict__ sdst,
        const half_t* __restrict__ hbuf16, const float* __restrict__ gb,
        const float* __restrict__ lng, const float* __restrict__ lnb,
        float* __restrict__ hseq) {
    int bid = blockIdx.x;
    int wg = (bid & 7) * (T*N/8) + (bid >> 3);   // XCD-contiguous node ranges
    int t = wg / N, n = wg % N;
    int tid = threadIdx.x;           // 128
    int myh = tid & 7;

    __shared__ int snarr[GCH];
    __shared__ float earr[GCH][H];
    __shared__ float red[128];
    __shared__ float sdl[H], mS[H], sS[H], scl[H];
    __shared__ float lnred[2];

    if (tid < H) {
        sdl[tid] = sdst[(t*N + n)*H + tid];
        mS[tid] = -3.0e38f;
        sS[tid] = 0.f;
    }
    float acc[H];
    #pragma unroll
    for (int h = 0; h < H; ++h) acc[h] = 0.f;
    int e0 = ia[I_START + n], e1 = ia[I_START + n + 1];
    __syncthreads();

    for (int c0 = e0; c0 < e1; c0 += GCH) {
        int cn = min(GCH, e1 - c0);
        if (tid < cn) {
            int j = ia[I_CSRE + c0 + tid];
            snarr[tid] = (j < E) ? ei[j] : (j - E);
        }
        __syncthreads();
        float lm = -3.0e38f;
        for (int w = tid; w < cn*H; w += 128) {
            int ce = w >> 3;
            float e = ssrc[(t*N + snarr[ce])*H + myh] + sdl[myh];
            e = (e > 0.f) ? e : 0.2f * e;
            earr[ce][myh] = e;
            lm = fmaxf(lm, e);
        }
        red[tid] = lm;
        __syncthreads();
        if (tid < H) {
            float cm = red[tid];
            #pragma unroll
            for (int k = 1; k < 16; ++k) cm = fmaxf(cm, red[tid + 8*k]);
            float mn = fmaxf(mS[tid], cm);
            scl[tid] = __expf(mS[tid] - mn);
            mS[tid] = mn;
        }
        __syncthreads();
        float ls = 0.f;
        float mh = mS[myh];
        for (int w = tid; w < cn*H; w += 128) {
            int ce = w >> 3;
            float p = __expf(earr[ce][myh] - mh);
            earr[ce][myh] = p;
            ls += p;
        }
        red[tid] = ls;
        __syncthreads();
        if (tid < H) {
            float cs = red[tid];
            #pragma unroll
            for (int k = 1; k < 16; ++k) cs += red[tid + 8*k];
            sS[tid] = sS[tid] * scl[tid] + cs;
        }
        #pragma unroll
        for (int h = 0; h < H; ++h) acc[h] *= scl[h];
        for (int ce = 0; ce < cn; ++ce) {
            const half_t* hp = hbuf16 + ((size_t)(t*N + snarr[ce]) * H) * D + tid;
            #pragma unroll
            for (int h = 0; h < H; ++h)
                acc[h] += earr[ce][h] * (float)hp[(size_t)h * D];
        }
        __syncthreads();
    }

    float v = 0.f;
    #pragma unroll
    for (int h = 0; h < H; ++h) v += acc[h] / sS[h];
    v = v * (1.f / H) + gb[tid];
    float mean = bsum(v, lnred, 2) * (1.f / D);
    float diff = v - mean;
    float var = bsum(diff * diff, lnred, 2) * (1.f / D);
    hseq[(size_t)(t*N + n) * D + tid] = diff * rsqrtf(var + 1e-5f) * lng[tid] + lnb[tid];
}

// ---------------- weight transpose + f16 convert ----------------
__global__ __launch_bounds__(256) void wconv_kernel(
        const float* __restrict__ Wqkv, const float* __restrict__ Wo,
        const float* __restrict__ W1, const float* __restrict__ W2,
        half_t* __restrict__ WqkvT, half_t* __restrict__ WoT,
        half_t* __restrict__ W1T, half_t* __restrict__ W2T) {
    int b = blockIdx.x;              // 3 * 576
    int l = b / 576, r = b % 576;
    const float* src; half_t* dst; int Rr, Cc, tr, tc;
    if (r < 48)       { src = Wqkv + (size_t)l*128*384;  dst = WqkvT + (size_t)l*384*128;  Rr=128;  Cc=384;  tc = r % 12;        tr = r / 12; }
    else if (r < 64)  { int rr=r-48;  src = Wo + (size_t)l*128*128;  dst = WoT + (size_t)l*128*128;  Rr=128;  Cc=128;  tc = rr % 4;  tr = rr / 4; }
    else if (r < 320) { int rr=r-64;  src = W1 + (size_t)l*128*2048; dst = W1T + (size_t)l*2048*128; Rr=128;  Cc=2048; tc = rr % 64; tr = rr / 64; }
    else              { int rr=r-320; src = W2 + (size_t)l*2048*128; dst = W2T + (size_t)l*128*2048; Rr=2048; Cc=128;  tc = rr % 4;  tr = rr / 4; }
    __shared__ float t[32][33];
    int tx = threadIdx.x & 31, ty = threadIdx.x >> 5;
    #pragma unroll
    for (int i = 0; i < 4; ++i) {
        int row = tr*32 + ty + i*8, col = tc*32 + tx;
        t[ty + i*8][tx] = src[(size_t)row * Cc + col];
    }
    __syncthreads();
    #pragma unroll
    for (int i = 0; i < 4; ++i) {
        int orow = tc*32 + ty + i*8, ocol = tr*32 + tx;
        dst[(size_t)orow * Rr + ocol] = (half_t)t[tx][ty + i*8];
    }
}

// ---------------- QKV via MFMA (32 tokens/block); optionally fuses previous layer's
// FFN reduce + bias + residual + LN into the staging phase (doRed != 0) ----------------
__global__ __launch_bounds__(256) void qkv_mfma_kernel(
        float* __restrict__ hseq, const float* __restrict__ ypart,
        const float* __restrict__ b2, const float* __restrict__ lng2,
        const float* __restrict__ lnb2, int doRed,
        const half_t* __restrict__ WqkvT, const float* __restrict__ bqkv,
        half_t* __restrict__ Qh, half_t* __restrict__ Kh, half_t* __restrict__ Vt) {
    __shared__ half_t xt[32*128];
    int tid = threadIdx.x;
    int s0 = blockIdx.x * 32;
    if (doRed) {
        int token = tid >> 3, part = tid & 7;
        int s = s0 + token;
        const float* hres = hseq + (size_t)s * 128;
        float v[16];
        #pragma unroll
        for (int i = 0; i < 16; ++i) v[i] = b2[part*16 + i] + hres[part*16 + i];
        #pragma unroll
        for (int fcc = 0; fcc < FCH; ++fcc) {
            const float* yp = ypart + ((size_t)fcc*S + s)*128 + part*16;
            #pragma unroll
            for (int i = 0; i < 16; ++i) v[i] += yp[i];
        }
        float sum = 0.f;
        #pragma unroll
        for (int i = 0; i < 16; ++i) sum += v[i];
        sum += __shfl_xor(sum, 1, 64); sum += __shfl_xor(sum, 2, 64); sum += __shfl_xor(sum, 4, 64);
        float mean = sum * (1.f/128.f);
        float vs = 0.f;
        #pragma unroll
        for (int i = 0; i < 16; ++i) { float dq = v[i] - mean; vs += dq*dq; }
        vs += __shfl_xor(vs, 1, 64); vs += __shfl_xor(vs, 2, 64); vs += __shfl_xor(vs, 4, 64);
        float inv = rsqrtf(vs * (1.f/128.f) + 1e-5f);
        half8 o0, o1;
        #pragma unroll
        for (int i = 0; i < 16; ++i) {
            int dim = part*16 + i;
            float ov = (v[i]-mean)*inv*lng2[dim] + lnb2[dim];
            hseq[(size_t)s*128 + dim] = ov;
            if (i < 8) o0[i] = (half_t)ov; else o1[i-8] = (half_t)ov;
        }
        *(half8*)swz_ptr(xt, token, part*16) = o0;
        *(half8*)swz_ptr(xt, token, part*16 + 8) = o1;
    } else {
        for (int c = tid; c < 512; c += 256) {
            int token = c >> 4, col8 = (c & 15) * 8;
            const float* src = hseq + (size_t)(s0 + token) * 128 + col8;
            float4 a = *(const float4*)src;
            float4 b = *(const float4*)(src + 4);
            half8 v;
            v[0]=(half_t)a.x; v[1]=(half_t)a.y; v[2]=(half_t)a.z; v[3]=(half_t)a.w;
            v[4]=(half_t)b.x; v[5]=(half_t)b.y; v[6]=(half_t)b.z; v[7]=(half_t)b.w;
            *(half8*)swz_ptr(xt, token, col8) = v;
        }
    }
    __syncthreads();
    int lane = tid & 63, w = tid >> 6;
    int lr = lane & 15, lg = lane >> 4;
    f32x4 acc[6][2];
    #pragma unroll
    for (int m = 0; m < 6; ++m)
        #pragma unroll
        for (int n = 0; n < 2; ++n) acc[m][n] = (f32x4){0.f, 0.f, 0.f, 0.f};
    #pragma unroll
    for (int ks = 0; ks < 4; ++ks) {
        half8 bf[2];
        #pragma unroll
        for (int n = 0; n < 2; ++n)
            bf[n] = *(half8*)swz_ptr(xt, n*16 + lr, ks*32 + lg*8);
        #pragma unroll
        for (int m = 0; m < 6; ++m) {
            int row = w*96 + m*16 + lr;
            half8 af = *(const half8*)(WqkvT + (size_t)row*128 + ks*32 + lg*8);
            #pragma unroll
            for (int n = 0; n < 2; ++n) acc[m][n] = MFMA16(af, bf[n], acc[m][n]);
        }
    }
    #pragma unroll
    for (int m = 0; m < 6; ++m) {
        int qd = w*96 + m*16 + lg*4;
        float4 bb = *(const float4*)(bqkv + qd);
        int part = qd >> 7, c = qd & 127, head = c >> 4, dd = c & 15;
        #pragma unroll
        for (int n = 0; n < 2; ++n) {
            int token = n*16 + lr;
            float v0 = acc[m][n][0] + bb.x, v1 = acc[m][n][1] + bb.y;
            float v2 = acc[m][n][2] + bb.z, v3 = acc[m][n][3] + bb.w;
            if (part == 0) {
                half4 hv = { (half_t)(v0*QSCALE), (half_t)(v1*QSCALE),
                             (half_t)(v2*QSCALE), (half_t)(v3*QSCALE) };
                *(half4*)(Qh + ((size_t)head*S + s0 + token)*HD + dd) = hv;
            } else if (part == 1) {
                half4 hv = { (half_t)v0, (half_t)v1, (half_t)v2, (half_t)v3 };
                *(half4*)(Kh + ((size_t)head*S + s0 + token)*HD + dd) = hv;
            } else {
                Vt[((size_t)head*HD + dd + 0)*S + s0 + token] = (half_t)v0;
                Vt[((size_t)head*HD + dd + 1)*S + s0 + token] = (half_t)v1;
                Vt[((size_t)head*HD + dd + 2)*S + s0 + token] = (half_t)v2;
                Vt[((size_t)head*HD + dd + 3)*S + s0 + token] = (half_t)v3;
            }
        }
    }
}

// ---------------- Attention v7: 32 queries/wave (128/block), 128-key LDS tiles ----------------
__global__ __launch_bounds__(256) void attn7_kernel(
        const half_t* __restrict__ Qh, const half_t* __restrict__ Kh,
        const half_t* __restrict__ Vt, float* __restrict__ pacc,
        float* __restrict__ pl) {
    int qb = blockIdx.x, h = blockIdx.y, ks = blockIdx.z;
    int tid = threadIdx.x;
    int lane = tid & 63;
    int w = tid >> 6;
    int lr = lane & 15, lg = lane >> 4;
    int qg0 = qb*128 + w*32 + lr;
    int qg1 = qg0 + 16;
    const f32x4 zf = {0.f, 0.f, 0.f, 0.f};

    __shared__ half_t kbuf[2][128*16];
    __shared__ half_t vbuf[2][16*VPAD2];

    half4 qf0 = *(const half4*)(Qh + ((size_t)h*S + qg0)*HD + lg*4);
    half4 qf1 = *(const half4*)(Qh + ((size_t)h*S + qg1)*HD + lg*4);

    int krow = tid >> 1, kch = tid & 1;
    int vdim = tid >> 4, vch = tid & 15;
    const half_t* Kbase = Kh + (size_t)h*S*HD;
    const half_t* Vbase = Vt + (size_t)h*HD*S;
    int kb0 = ks*(S/KS);

    *(half8*)&kbuf[0][krow*16 + kch*8] = *(const half8*)(Kbase + (size_t)(kb0+krow)*HD + kch*8);
    *(half8*)&vbuf[0][vdim*VPAD2 + vch*8] = *(const half8*)(Vbase + (size_t)vdim*S + kb0 + vch*8);
    __syncthreads();

    float l0 = 0.f, l1 = 0.f;
    f32x4 oa0 = zf, oa1 = zf, ob0 = zf, ob1 = zf;
    int cur = 0;
    const int NT = (S/KS)/128;               // 6
    for (int t = 0; t < NT; ++t) {
        half8 knext, vnext;
        if (t+1 < NT) {
            int kbn = kb0 + (t+1)*128;
            knext = *(const half8*)(Kbase + (size_t)(kbn+krow)*HD + kch*8);
            vnext = *(const half8*)(Vbase + (size_t)vdim*S + kbn + vch*8);
        }

        f32x4 sc0[8], sc1[8];
        #pragma unroll
        for (int ct = 0; ct < 8; ++ct) {
            half4 kf = *(half4*)&kbuf[cur][(ct*16+lr)*16 + lg*4];
            sc0[ct] = MFMA16K16(kf, qf0, zf);
            sc1[ct] = MFMA16K16(kf, qf1, zf);
        }
        half4 pf0[8], pf1[8];
        #pragma unroll
        for (int ct = 0; ct < 8; ++ct)
            #pragma unroll
            for (int r = 0; r < 4; ++r) {
                float pv0 = exp2f(sc0[ct][r] - SM_SHIFT2);
                float pv1 = exp2f(sc1[ct][r] - SM_SHIFT2);
                l0 += pv0; l1 += pv1;
                pf0[ct][r] = (half_t)pv0;
                pf1[ct][r] = (half_t)pv1;
            }
        #pragma unroll
        for (int ct = 0; ct < 8; ++ct) {
            half4 vf = *(half4*)&vbuf[cur][lr*VPAD2 + ct*16 + lg*4];
            if (ct & 1) { oa1 = MFMA16K16(vf, pf0[ct], oa1); ob1 = MFMA16K16(vf, pf1[ct], ob1); }
            else        { oa0 = MFMA16K16(vf, pf0[ct], oa0); ob0 = MFMA16K16(vf, pf1[ct], ob0); }
        }
        if (t+1 < NT) {
            *(half8*)&kbuf[cur^1][krow*16 + kch*8] = knext;
            *(half8*)&vbuf[cur^1][vdim*VPAD2 + vch*8] = vnext;
            __syncthreads();
            cur ^= 1;
        }
    }
    oa0[0]+=oa1[0]; oa0[1]+=oa1[1]; oa0[2]+=oa1[2]; oa0[3]+=oa1[3];
    ob0[0]+=ob1[0]; ob0[1]+=ob1[1]; ob0[2]+=ob1[2]; ob0[3]+=ob1[3];

    l0 += __shfl_xor(l0, 16, 64); l0 += __shfl_xor(l0, 32, 64);
    l1 += __shfl_xor(l1, 16, 64); l1 += __shfl_xor(l1, 32, 64);

    size_t oi0 = ((size_t)(ks*H + h) * S + qg0);
    size_t oi1 = ((size_t)(ks*H + h) * S + qg1);
    if (lg == 0) { pl[oi0] = l0; pl[oi1] = l1; }
    #pragma unroll
    for (int r = 0; r < 4; ++r) {
        pacc[oi0 * HD + lg*4 + r] = oa0[r];
        pacc[oi1 * HD + lg*4 + r] = ob0[r];
    }
}

// ---------------- out-proj + residual + LN via MFMA (32 tokens/block), attn-combine fused ----------------
__global__ __launch_bounds__(256) void oproj_mfma_ln_kernel(
        const float* __restrict__ pacc, const float* __restrict__ pl,
        const half_t* __restrict__ WoT,
        const float* __restrict__ bo, const float* __restrict__ lng,
        const float* __restrict__ lnb, float* __restrict__ hseq) {
    __shared__ half_t xt[32*128];
    __shared__ float yt[32*132];
    int tid = threadIdx.x;
    int s0 = blockIdx.x * 32;
    for (int c = tid; c < 512; c += 256) {
        int token = c >> 4, col8 = (c & 15) * 8;
        int s = s0 + token;
        int h = col8 >> 4, dd0 = col8 & 15;
        float L = 0.f;
        float a[8] = {0,0,0,0,0,0,0,0};
        #pragma unroll
        for (int k = 0; k < KS; ++k) {
            size_t oi = ((size_t)(k*H + h) * S + s);
            L += pl[oi];
            const float* pp = pacc + oi * HD + dd0;
            float4 p0 = *(const float4*)pp;
            float4 p1 = *(const float4*)(pp + 4);
            a[0]+=p0.x; a[1]+=p0.y; a[2]+=p0.z; a[3]+=p0.w;
            a[4]+=p1.x; a[5]+=p1.y; a[6]+=p1.z; a[7]+=p1.w;
        }
        float inv = 1.f / L;
        half8 v;
        #pragma unroll
        for (int i = 0; i < 8; ++i) v[i] = (half_t)(a[i] * inv);
        *(half8*)swz_ptr(xt, token, col8) = v;
    }
    __syncthreads();
    int lane = tid & 63, w = tid >> 6;
    int lr = lane & 15, lg = lane >> 4;
    f32x4 acc[2][2];
    #pragma unroll
    for (int m = 0; m < 2; ++m)
        #pragma unroll
        for (int n = 0; n < 2; ++n) acc[m][n] = (f32x4){0.f, 0.f, 0.f, 0.f};
    #pragma unroll
    for (int kk = 0; kk < 4; ++kk) {
        half8 bf[2];
        #pragma unroll
        for (int n = 0; n < 2; ++n)
            bf[n] = *(half8*)swz_ptr(xt, n*16 + lr, kk*32 + lg*8);
        #pragma unroll
        for (int m = 0; m < 2; ++m) {
            int row = w*32 + m*16 + lr;
            half8 af = *(const half8*)(WoT + (size_t)row*128 + kk*32 + lg*8);
            #pragma unroll
            for (int n = 0; n < 2; ++n) acc[m][n] = MFMA16(af, bf[n], acc[m][n]);
        }
    }
    #pragma unroll
    for (int m = 0; m < 2; ++m)
        #pragma unroll
        for (int n = 0; n < 2; ++n) {
            int token = n*16 + lr;
            int od = w*32 + m*16 + lg*4;
            *(f32x4*)&yt[token*132 + od] = acc[m][n];
        }
    __syncthreads();
    {
        int token = tid >> 3, part = tid & 7;
        const float* hres = hseq + (size_t)(s0 + token) * 128;
        float v[16];
        float sum = 0.f;
        #pragma unroll
        for (int i = 0; i < 16; ++i) {
            int dim = part*16 + i;
            v[i] = yt[token*132 + dim] + bo[dim] + hres[dim];
            sum += v[i];
        }
        sum += __shfl_xor(sum, 1, 64); sum += __shfl_xor(sum, 2, 64); sum += __shfl_xor(sum, 4, 64);
        float mean = sum * (1.f/128.f);
        float vs = 0.f;
        #pragma unroll
        for (int i = 0; i < 16; ++i) { float dq = v[i] - mean; vs += dq*dq; }
        vs += __shfl_xor(vs, 1, 64); vs += __shfl_xor(vs, 2, 64); vs += __shfl_xor(vs, 4, 64);
        float inv = rsqrtf(vs * (1.f/128.f) + 1e-5f);
        #pragma unroll
        for (int i = 0; i < 16; ++i) {
            int dim = part*16 + i;
            hseq[(size_t)(s0+token)*128 + dim] = (v[i]-mean)*inv*lng[dim] + lnb[dim];
        }
    }
}

// ---------------- FFN split-FF: grid (96, FCH) -> partial Y into ypart ----------------
__global__ __launch_bounds__(256) void ffn_mfma2_kernel(
        const half_t* __restrict__ W1T, const half_t* __restrict__ W2T,
        const float* __restrict__ b1, const float* __restrict__ hseq,
        float* __restrict__ ypart) {
    __shared__ half_t xt[32*128];      // 8 KB
    __shared__ half_t h1[32*256];      // 16 KB
    int tid = threadIdx.x;             // 256
    int s0 = blockIdx.x * 32;
    int fc = blockIdx.y;
    int fbase = fc * 256;
    for (int c = tid; c < 512; c += 256) {
        int token = c >> 4, col8 = (c & 15) * 8;
        const float* src = hseq + (size_t)(s0 + token) * 128 + col8;
        float4 a = *(const float4*)src;
        float4 b = *(const float4*)(src + 4);
        half8 v;
        v[0]=(half_t)a.x; v[1]=(half_t)a.y; v[2]=(half_t)a.z; v[3]=(half_t)a.w;
        v[4]=(half_t)b.x; v[5]=(half_t)b.y; v[6]=(half_t)b.z; v[7]=(half_t)b.w;
        *(half8*)swz_ptr(xt, token, col8) = v;
    }
    __syncthreads();
    int lane = tid & 63, mw = tid >> 6;
    int lr = lane & 15, lg = lane >> 4;

    f32x4 hacc[4][2];
    #pragma unroll
    for (int m = 0; m < 4; ++m)
        #pragma unroll
        for (int n = 0; n < 2; ++n) hacc[m][n] = (f32x4){0.f, 0.f, 0.f, 0.f};
    #pragma unroll
    for (int ksx = 0; ksx < 4; ++ksx) {
        half8 bf[2];
        #pragma unroll
        for (int n = 0; n < 2; ++n)
            bf[n] = *(half8*)swz_ptr(xt, n*16 + lr, ksx*32 + lg*8);
        #pragma unroll
        for (int m = 0; m < 4; ++m) {
            int row = fbase + mw*64 + m*16 + lr;
            half8 af = *(const half8*)(W1T + (size_t)row*128 + ksx*32 + lg*8);
            #pragma unroll
            for (int n = 0; n < 2; ++n) hacc[m][n] = MFMA16(af, bf[n], hacc[m][n]);
        }
    }
    #pragma unroll
    for (int m = 0; m < 4; ++m) {
        int frow = mw*64 + m*16 + lg*4;
        float4 bb = *(const float4*)(b1 + fbase + frow);
        #pragma unroll
        for (int n = 0; n < 2; ++n) {
            int token = n*16 + lr;
            half4 hv;
            hv[0] = (half_t)fmaxf(hacc[m][n][0] + bb.x, 0.f);
            hv[1] = (half_t)fmaxf(hacc[m][n][1] + bb.y, 0.f);
            hv[2] = (half_t)fmaxf(hacc[m][n][2] + bb.z, 0.f);
            hv[3] = (half_t)fmaxf(hacc[m][n][3] + bb.w, 0.f);
            *(half4*)swz_ptr256(h1, token, frow) = hv;
        }
    }
    __syncthreads();

    f32x4 yacc[2][2];
    #pragma unroll
    for (int m = 0; m < 2; ++m)
        #pragma unroll
        for (int n = 0; n < 2; ++n) yacc[m][n] = (f32x4){0.f, 0.f, 0.f, 0.f};
    #pragma unroll
    for (int ksx = 0; ksx < 8; ++ksx) {
        half8 bf[2];
        #pragma unroll
        for (int n = 0; n < 2; ++n)
            bf[n] = *(half8*)swz_ptr256(h1, n*16 + lr, ksx*32 + lg*8);
        #pragma unroll
        for (int m = 0; m < 2; ++m) {
            int row = mw*32 + m*16 + lr;
            half8 af = *(const half8*)(W2T + (size_t)row*2048 + fbase + ksx*32 + lg*8);
            #pragma unroll
            for (int n = 0; n < 2; ++n) yacc[m][n] = MFMA16(af, bf[n], yacc[m][n]);
        }
    }
    #pragma unroll
    for (int m = 0; m < 2; ++m)
        #pragma unroll
        for (int n = 0; n < 2; ++n) {
            int token = n*16 + lr;
            int od = mw*32 + m*16 + lg*4;
            *(f32x4*)&ypart[((size_t)fc*S + s0 + token)*128 + od] = yacc[m][n];
        }
}

// ---------------- FFN reduce + LN + pool partials + (last block) heads ----------------
__global__ __launch_bounds__(256) void ffn_reduce_ln_pool_kernel(
        const float* __restrict__ ypart, const float* __restrict__ b2,
        const float* __restrict__ lng, const float* __restrict__ lnb,
        float* __restrict__ hseq, float* __restrict__ gpart, int* __restrict__ cnt,
        const float* __restrict__ rW1, const float* __restrict__ rb1,
        const float* __restrict__ rW2, const float* __restrict__ rb2,
        const float* __restrict__ mW1, const float* __restrict__ mb1,
        const float* __restrict__ mW2, const float* __restrict__ mb2,
        const float* __restrict__ uW1, const float* __restrict__ ub1,
        const float* __restrict__ uW2, const float* __restrict__ ub2,
        float* __restrict__ out) {
    __shared__ float wsum[4][128];
    __shared__ int isLast;
    int tid = threadIdx.x;             // 256: 64 tokens x 4 parts
    int token = blockIdx.x * 64 + (tid >> 2);
    int part = tid & 3;                // 32 dims each
    int lane = tid & 63, wv = tid >> 6;
    const float* hres = hseq + (size_t)token * 128;
    float v[32];
    #pragma unroll
    for (int i = 0; i < 32; ++i) {
        int dim = part*32 + i;
        v[i] = b2[dim] + hres[dim];
    }
    #pragma unroll
    for (int fcc = 0; fcc < FCH; ++fcc) {
        const float* yp = ypart + ((size_t)fcc*S + token)*128 + part*32;
        #pragma unroll
        for (int i = 0; i < 32; ++i) v[i] += yp[i];
    }
    float sum = 0.f;
    #pragma unroll
    for (int i = 0; i < 32; ++i) sum += v[i];
    sum += __shfl_xor(sum, 1, 64); sum += __shfl_xor(sum, 2, 64);
    float mean = sum * (1.f/128.f);
    float vs = 0.f;
    #pragma unroll
    for (int i = 0; i < 32; ++i) { float dq = v[i] - mean; vs += dq*dq; }
    vs += __shfl_xor(vs, 1, 64); vs += __shfl_xor(vs, 2, 64);
    float inv = rsqrtf(vs * (1.f/128.f) + 1e-5f);
    float o[32];
    #pragma unroll
    for (int i = 0; i < 32; ++i) {
        int dim = part*32 + i;
        o[i] = (v[i]-mean)*inv*lng[dim] + lnb[dim];
        hseq[(size_t)token*128 + dim] = o[i];
    }
    // pool partial: sum o[] across the 16 tokens of this wave
    #pragma unroll
    for (int i = 0; i < 32; ++i) {
        o[i] += __shfl_xor(o[i], 4, 64);
        o[i] += __shfl_xor(o[i], 8, 64);
        o[i] += __shfl_xor(o[i], 16, 64);
        o[i] += __shfl_xor(o[i], 32, 64);
    }
    if (lane < 4) {
        #pragma unroll
        for (int i = 0; i < 32; ++i) wsum[wv][lane*32 + i] = o[i];
    }
    __syncthreads();
    if (tid < 128)
        gpart[(size_t)blockIdx.x * 128 + tid] =
            wsum[0][tid] + wsum[1][tid] + wsum[2][tid] + wsum[3][tid];

    // ---- completion: last block computes the heads ----
    __threadfence();
    __syncthreads();
    if (tid == 0) isLast = (atomicAdd(cnt, 1) == NB - 1);
    __syncthreads();
    if (!isLast) return;
    __threadfence();                 // acquire: see all gpart writes
    if (tid == 0) *cnt = 0;          // reset for next graph replay

    __shared__ float gl[D];
    __shared__ float r1[64];
    __shared__ float mh[32];
    __shared__ float uh[32];
    if (tid < 128) {
        float acc = 0.f;
        for (int b = 0; b < NB; ++b) acc += gpart[(size_t)b * 128 + tid];
        gl[tid] = acc * (1.f / S);
    }
    __syncthreads();
    if (tid < 64) {
        float acc = rb1[tid];
        for (int k = 0; k < D; ++k) acc += gl[k] * rW1[k * 64 + tid];
        r1[tid] = fmaxf(acc, 0.f);
    }
    if (tid >= 64 && tid < 96) {
        int t = tid - 64;
        float am = mb1[t], au = ub1[t];
        for (int k = 0; k < D; ++k) {
            am += gl[k] * mW1[k * 32 + t];
            au += gl[k] * uW1[k * 32 + t];
        }
        mh[t] = fmaxf(am, 0.f);
        uh[t] = fmaxf(au, 0.f);
    }
    __syncthreads();
    if (tid == 0) {
        float acc = rb2[0];
        for (int k = 0; k < 64; ++k) acc += r1[k] * rW2[k];
        out[0] = 1.f / (1.f + __expf(-acc));
    }
    if (tid >= 8 && tid < 16) {
        int t = tid - 8;
        float acc = mb2[t];
        for (int k = 0; k < 32; ++k) acc += mh[k] * mW2[k * 8 + t];
        out[1 + t] = acc;
    }
    if (tid >= 16 && tid < 18) {
        int t = tid - 16;
        float acc = ub2[t];
        for (int k = 0; k < 32; ++k) acc += uh[k] * uW2[k * 2 + t];
        out[9 + t] = (acc > 20.f) ? acc : log1pf(__expf(acc));
    }
}

extern "C" void kernel_launch(void* const* d_in, const int* in_sizes, int n_in,
                              void* d_out, int out_size, void* d_ws, size_t ws_size,
                              hipStream_t stream) {
    const float* x       = (const float*)d_in[0];
    const int*   ei      = (const int*)  d_in[1];
    const float* gat_W   = (const float*)d_in[2];
    const float* gat_asrc= (const float*)d_in[3];
    const float* gat_adst= (const float*)d_in[4];
    const float* gat_b   = (const float*)d_in[5];
    const float* ln_g    = (const float*)d_in[6];
    const float* ln_b    = (const float*)d_in[7];
    const float* Wqkv    = (const float*)d_in[8];
    const float* bqkv    = (const float*)d_in[9];
    const float* Wo      = (const float*)d_in[10];
    const float* bo      = (const float*)d_in[11];
    const float* ln1g    = (const float*)d_in[12];
    const float* ln1b    = (const float*)d_in[13];
    const float* W1      = (const float*)d_in[14];
    const float* b1      = (const float*)d_in[15];
    const float* W2      = (const float*)d_in[16];
    const float* b2      = (const float*)d_in[17];
    const float* ln2g    = (const float*)d_in[18];
    const float* ln2b    = (const float*)d_in[19];
    const float* rW1     = (const float*)d_in[20];
    const float* rb1     = (const float*)d_in[21];
    const float* rW2     = (const float*)d_in[22];
    const float* rb2     = (const float*)d_in[23];
    const float* mW1     = (const float*)d_in[24];
    const float* mb1     = (const float*)d_in[25];
    const float* mW2     = (const float*)d_in[26];
    const float* mb2     = (const float*)d_in[27];
    const float* uW1     = (const float*)d_in[28];
    const float* ub1     = (const float*)d_in[29];
    const float* uW2     = (const float*)d_in[30];
    const float* ub2     = (const float*)d_in[31];

    float* ws = (float*)d_ws;
    half_t*       hbuf16 = (half_t*)(ws + O_A);
    half_t*       Qh   = (half_t*)(ws + O_A);
    half_t*       Kh   = Qh + (size_t)H*S*HD;
    half_t*       Vt   = Kh + (size_t)H*S*HD;
    half_t*       wb   = (half_t*)(ws + O_A + WB_OFF);
    half_t*       WqkvT= wb + WB_QKV;
    half_t*       WoT  = wb + WB_WO;
    half_t*       W1T  = wb + WB_W1;
    half_t*       W2T  = wb + WB_W2;
    float*        pacc = ws + O_C;
    float*        ypart= ws + O_C;
    float*        pl   = ws + O_C + (size_t)KS*H*S*HD;
    float*        hseq = ws + O_HSEQ;
    float*        ssrc = ws + O_SSRC;
    float*        sdst = ws + O_SDST;
    int*          ia   = (int*)(ws + O_INT);
    float*        gpart= ws + O_G;
    int*          cnt  = (int*)(ws + O_CNT);
    float* out = (float*)d_out;

    // ---- GAT ----
    gat_lin_kernel<<<dim3(T*N), dim3(256), 0, stream>>>(x, gat_W, gat_asrc, gat_adst,
                                                        hbuf16, ssrc, sdst);
    csr_build_kernel<<<dim3(1), dim3(512), 0, stream>>>(ei, ia, cnt);
    gat_fused_kernel<<<dim3(T*N), dim3(128), 0, stream>>>(
        ei, ia, ssrc, sdst, hbuf16, gat_b, ln_g, ln_b, hseq);

    // ---- weight convert ----
    wconv_kernel<<<dim3(3*576), dim3(256), 0, stream>>>(Wqkv, Wo, W1, W2, WqkvT, WoT, W1T, W2T);

    // ---- transformer layers ----
    for (int l = 0; l < 3; ++l) {
        qkv_mfma_kernel<<<dim3(S/32), dim3(256), 0, stream>>>(
            hseq, ypart, b2 + (l-1)*D, ln2g + (l-1)*D, ln2b + (l-1)*D, (l > 0) ? 1 : 0,
            WqkvT + (size_t)l*384*128, bqkv + l*3*D, Qh, Kh, Vt);
        attn7_kernel<<<dim3(S/128, H, KS), dim3(256), 0, stream>>>(Qh, Kh, Vt, pacc, pl);
        oproj_mfma_ln_kernel<<<dim3(S/32), dim3(256), 0, stream>>>(
            pacc, pl, WoT + (size_t)l*128*128, bo + l*D, ln1g + l*D, ln1b + l*D, hseq);
        ffn_mfma2_kernel<<<dim3(S/32, FCH), dim3(256), 0, stream>>>(
            W1T + (size_t)l*2048*128, W2T + (size_t)l*128*2048,
            b1 + l*FF, hseq, ypart);
    }
    // last layer's FFN reduce + LN + pool partials + heads (fused, last-block)
    ffn_reduce_ln_pool_kernel<<<dim3(NB), dim3(256), 0, stream>>>(
        ypart, b2 + 2*D, ln2g + 2*D, ln2b + 2*D, hseq, gpart, cnt,
        rW1, rb1, rW2, rb2, mW1, mb1, mW2, mb2, uW1, ub1, uW2, ub2, out);
}

// Round 16
// 274.179 us; speedup vs baseline: 1.0537x; 1.0247x over previous
//
#include <hip/hip_runtime.h>
#include <hip/hip_bf16.h>
#include <math.h>

#define T 6
#define N 512
#define E 16384
#define EN (E + N)      // 16896 with self loops
#define H 8
#define D 128
#define HD 16
#define S (T * N)       // 3072
#define FIN 15
#define FF 2048
#define KS 4            // attention key-split
#define FCH 8           // FFN ff-chunk count (256 ff rows each)
#define GCH 64          // GAT edge chunk
#define NB (S/64)       // ffn_reduce blocks == pool partials (48)
#define SM_SHIFT2 2.88539008f   // static softmax shift, log2 domain
#define QSCALE 0.36067376f      // 0.25 * log2(e)
#define VPAD2 136       // V LDS row stride in halfs

typedef _Float16 half_t;
typedef _Float16 half8 __attribute__((ext_vector_type(8)));
typedef _Float16 half4 __attribute__((ext_vector_type(4)));
typedef float f32x4 __attribute__((ext_vector_type(4)));

#define MFMA16(a, b, c) __builtin_amdgcn_mfma_f32_16x16x32_f16(a, b, c, 0, 0, 0)
#define MFMA16K16(a, b, c) __builtin_amdgcn_mfma_f32_16x16x16f16(a, b, c, 0, 0, 0)

// ---------------- workspace layout (floats) ----------------
#define O_A      0
#define O_EBUF   (T*N*H*D)
#define O_C      (O_EBUF + T*EN*H)         // attn partials / ffn ypart
#define O_HSEQ   (O_C + T*N*H*D)
#define O_OBUF   (O_HSEQ + S*D)
#define O_SSRC   (O_OBUF + S*D)
#define O_SDST   (O_SSRC + T*N*H)
#define O_INT    (O_SDST + T*N*H)
#define O_G      (O_INT + 20000)           // gpart[NB][128]

// int-area offsets (ints, relative to O_INT)
#define I_START  0                         // [N+1]
#define I_CSRE   513                       // [EN]

// f16 weight area: inside O_A after Qh/Kh/Vt f16
#define WB_OFF   (3*H*S*HD)
#define WB_QKV   0
#define WB_WO    147456
#define WB_W1    196608
#define WB_W2    983040

__device__ __forceinline__ float bsum(float v, float* lds, int nw) {
    #pragma unroll
    for (int off = 32; off > 0; off >>= 1) v += __shfl_down(v, off, 64);
    int w = threadIdx.x >> 6;
    if ((threadIdx.x & 63) == 0) lds[w] = v;
    __syncthreads();
    float r = 0.f;
    for (int i = 0; i < nw; ++i) r += lds[i];
    __syncthreads();
    return r;
}

// swizzled pointer into a [rows][128] f16 LDS tile (row stride 256 B)
__device__ __forceinline__ half_t* swz_ptr(half_t* base, int token, int col) {
    int byte = token * 256 + col * 2;
    byte ^= (token & 7) << 4;
    return (half_t*)((char*)base + byte);
}
// swizzled pointer into a [rows][256] f16 LDS tile (row stride 512 B)
__device__ __forceinline__ half_t* swz_ptr256(half_t* base, int token, int col) {
    int byte = token * 512 + col * 2;
    byte ^= (token & 7) << 4;
    return (half_t*)((char*)base + byte);
}

// ---------------- GAT: lin + per-(t,n,head) src/dst scores fused ----------------
__global__ __launch_bounds__(256) void gat_lin_kernel(
        const float* __restrict__ x, const float* __restrict__ W,
        const float* __restrict__ asrc, const float* __restrict__ adst,
        half_t* __restrict__ hbuf16, float* __restrict__ ssrc, float* __restrict__ sdst) {
    int r = blockIdx.x;
    int tid = threadIdx.x;           // 256
    __shared__ float xr[FIN];
    __shared__ float hl[H*D];        // 4 KB
    if (tid < FIN) xr[tid] = x[r * FIN + tid];
    __syncthreads();
    #pragma unroll
    for (int kk = 0; kk < 4; ++kk) {
        int col = tid + kk * 256;
        float acc = 0.f;
        #pragma unroll
        for (int f = 0; f < FIN; ++f) acc += xr[f] * W[f * (H*D) + col];
        hbuf16[(size_t)r * (H*D) + col] = (half_t)acc;
        hl[col] = acc;
    }
    __syncthreads();
    int w = tid >> 6, lane = tid & 63;
    #pragma unroll
    for (int i = 0; i < 4; ++i) {
        int p = w*4 + i;
        int head = p >> 1;
        const float* av = ((p & 1) ? adst : asrc) + head * D;
        float v = hl[head*D + lane] * av[lane] + hl[head*D + 64 + lane] * av[64 + lane];
        #pragma unroll
        for (int off = 32; off > 0; off >>= 1) v += __shfl_down(v, off, 64);
        if (lane == 0) {
            if (p & 1) sdst[r*H + head] = v;
            else       ssrc[r*H + head] = v;
        }
    }
}

// ---------------- CSR build: count + scan + fill, one block, all in LDS ----------------
__global__ __launch_bounds__(512) void csr_build_kernel(const int* __restrict__ ei, int* ia) {
    __shared__ int deg[N];           // degree, then reused as cursor
    __shared__ int buf[N];
    int tid = threadIdx.x;           // 512 == N
    deg[tid] = 0;
    __syncthreads();
    for (int j = tid; j < EN; j += 512) {
        int dn = (j < E) ? ei[E + j] : (j - E);
        atomicAdd(&deg[dn], 1);
    }
    __syncthreads();
    int v = deg[tid];
    buf[tid] = v;
    __syncthreads();
    for (int off = 1; off < N; off <<= 1) {
        int t = (tid >= off) ? buf[tid - off] : 0;
        __syncthreads();
        buf[tid] += t;
        __syncthreads();
    }
    ia[I_START + tid + 1] = buf[tid];
    if (tid == 0) ia[I_START] = 0;
    deg[tid] = buf[tid] - v;         // exclusive cursor
    __syncthreads();
    for (int j = tid; j < EN; j += 512) {
        int dn = (j < E) ? ei[E + j] : (j - E);
        int slot = atomicAdd(&deg[dn], 1);
        ia[I_CSRE + slot] = j;
    }
}

// ---------------- GAT fused: edge softmax (online, chunked) + gather + head-mean + LN ----------------
__global__ __launch_bounds__(128) void gat_fused_kernel(
        const int* __restrict__ ei, const int* __restrict__ ia,
        const float* __restrict__ ssrc, const float* __restrict__ sdst,
        const half_t* __restrict__ hbuf16, const float* __restrict__ gb,
        const float* __restrict__ lng, const float* __restrict__ lnb,
        float* __restrict__ hseq) {
    int bid = blockIdx.x;
    int wg = (bid & 7) * (T*N/8) + (bid >> 3);   // XCD-contiguous node ranges
    int t = wg / N, n = wg % N;
    int tid = threadIdx.x;           // 128
    int myh = tid & 7;

    __shared__ int snarr[GCH];
    __shared__ float earr[GCH][H];
    __shared__ float red[128];
    __shared__ float sdl[H], mS[H], sS[H], scl[H];
    __shared__ float lnred[2];

    if (tid < H) {
        sdl[tid] = sdst[(t*N + n)*H + tid];
        mS[tid] = -3.0e38f;
        sS[tid] = 0.f;
    }
    float acc[H];
    #pragma unroll
    for (int h = 0; h < H; ++h) acc[h] = 0.f;
    int e0 = ia[I_START + n], e1 = ia[I_START + n + 1];
    __syncthreads();

    for (int c0 = e0; c0 < e1; c0 += GCH) {
        int cn = min(GCH, e1 - c0);
        if (tid < cn) {
            int j = ia[I_CSRE + c0 + tid];
            snarr[tid] = (j < E) ? ei[j] : (j - E);
        }
        __syncthreads();
        float lm = -3.0e38f;
        for (int w = tid; w < cn*H; w += 128) {
            int ce = w >> 3;
            float e = ssrc[(t*N + snarr[ce])*H + myh] + sdl[myh];
            e = (e > 0.f) ? e : 0.2f * e;
            earr[ce][myh] = e;
            lm = fmaxf(lm, e);
        }
        red[tid] = lm;
        __syncthreads();
        if (tid < H) {
            float cm = red[tid];
            #pragma unroll
            for (int k = 1; k < 16; ++k) cm = fmaxf(cm, red[tid + 8*k]);
            float mn = fmaxf(mS[tid], cm);
            scl[tid] = __expf(mS[tid] - mn);
            mS[tid] = mn;
        }
        __syncthreads();
        float ls = 0.f;
        float mh = mS[myh];
        for (int w = tid; w < cn*H; w += 128) {
            int ce = w >> 3;
            float p = __expf(earr[ce][myh] - mh);
            earr[ce][myh] = p;
            ls += p;
        }
        red[tid] = ls;
        __syncthreads();
        if (tid < H) {
            float cs = red[tid];
            #pragma unroll
            for (int k = 1; k < 16; ++k) cs += red[tid + 8*k];
            sS[tid] = sS[tid] * scl[tid] + cs;
        }
        #pragma unroll
        for (int h = 0; h < H; ++h) acc[h] *= scl[h];
        for (int ce = 0; ce < cn; ++ce) {
            const half_t* hp = hbuf16 + ((size_t)(t*N + snarr[ce]) * H) * D + tid;
            #pragma unroll
            for (int h = 0; h < H; ++h)
                acc[h] += earr[ce][h] * (float)hp[(size_t)h * D];
        }
        __syncthreads();
    }

    float v = 0.f;
    #pragma unroll
    for (int h = 0; h < H; ++h) v += acc[h] / sS[h];
    v = v * (1.f / H) + gb[tid];
    float mean = bsum(v, lnred, 2) * (1.f / D);
    float diff = v - mean;
    float var = bsum(diff * diff, lnred, 2) * (1.f / D);
    hseq[(size_t)(t*N + n) * D + tid] = diff * rsqrtf(var + 1e-5f) * lng[tid] + lnb[tid];
}

// ---------------- weight transpose + f16 convert ----------------
__global__ __launch_bounds__(256) void wconv_kernel(
        const float* __restrict__ Wqkv, const float* __restrict__ Wo,
        const float* __restrict__ W1, const float* __restrict__ W2,
        half_t* __restrict__ WqkvT, half_t* __restrict__ WoT,
        half_t* __restrict__ W1T, half_t* __restrict__ W2T) {
    int b = blockIdx.x;              // 3 * 576
    int l = b / 576, r = b % 576;
    const float* src; half_t* dst; int Rr, Cc, tr, tc;
    if (r < 48)       { src = Wqkv + (size_t)l*128*384;  dst = WqkvT + (size_t)l*384*128;  Rr=128;  Cc=384;  tc = r % 12;        tr = r / 12; }
    else if (r < 64)  { int rr=r-48;  src = Wo + (size_t)l*128*128;  dst = WoT + (size_t)l*128*128;  Rr=128;  Cc=128;  tc = rr % 4;  tr = rr / 4; }
    else if (r < 320) { int rr=r-64;  src = W1 + (size_t)l*128*2048; dst = W1T + (size_t)l*2048*128; Rr=128;  Cc=2048; tc = rr % 64; tr = rr / 64; }
    else              { int rr=r-320; src = W2 + (size_t)l*2048*128; dst = W2T + (size_t)l*128*2048; Rr=2048; Cc=128;  tc = rr % 4;  tr = rr / 4; }
    __shared__ float t[32][33];
    int tx = threadIdx.x & 31, ty = threadIdx.x >> 5;
    #pragma unroll
    for (int i = 0; i < 4; ++i) {
        int row = tr*32 + ty + i*8, col = tc*32 + tx;
        t[ty + i*8][tx] = src[(size_t)row * Cc + col];
    }
    __syncthreads();
    #pragma unroll
    for (int i = 0; i < 4; ++i) {
        int orow = tc*32 + ty + i*8, ocol = tr*32 + tx;
        dst[(size_t)orow * Rr + ocol] = (half_t)t[tx][ty + i*8];
    }
}

// ---------------- QKV via MFMA (32 tokens/block); optionally fuses previous layer's
// FFN reduce + bias + residual + LN into the staging phase (doRed != 0) ----------------
__global__ __launch_bounds__(256) void qkv_mfma_kernel(
        float* __restrict__ hseq, const float* __restrict__ ypart,
        const float* __restrict__ b2, const float* __restrict__ lng2,
        const float* __restrict__ lnb2, int doRed,
        const half_t* __restrict__ WqkvT, const float* __restrict__ bqkv,
        half_t* __restrict__ Qh, half_t* __restrict__ Kh, half_t* __restrict__ Vt) {
    __shared__ half_t xt[32*128];
    int tid = threadIdx.x;
    int s0 = blockIdx.x * 32;
    if (doRed) {
        int token = tid >> 3, part = tid & 7;
        int s = s0 + token;
        const float* hres = hseq + (size_t)s * 128;
        float v[16];
        #pragma unroll
        for (int i = 0; i < 16; ++i) v[i] = b2[part*16 + i] + hres[part*16 + i];
        #pragma unroll
        for (int fcc = 0; fcc < FCH; ++fcc) {
            const float* yp = ypart + ((size_t)fcc*S + s)*128 + part*16;
            #pragma unroll
            for (int i = 0; i < 16; ++i) v[i] += yp[i];
        }
        float sum = 0.f;
        #pragma unroll
        for (int i = 0; i < 16; ++i) sum += v[i];
        sum += __shfl_xor(sum, 1, 64); sum += __shfl_xor(sum, 2, 64); sum += __shfl_xor(sum, 4, 64);
        float mean = sum * (1.f/128.f);
        float vs = 0.f;
        #pragma unroll
        for (int i = 0; i < 16; ++i) { float dq = v[i] - mean; vs += dq*dq; }
        vs += __shfl_xor(vs, 1, 64); vs += __shfl_xor(vs, 2, 64); vs += __shfl_xor(vs, 4, 64);
        float inv = rsqrtf(vs * (1.f/128.f) + 1e-5f);
        half8 o0, o1;
        #pragma unroll
        for (int i = 0; i < 16; ++i) {
            int dim = part*16 + i;
            float ov = (v[i]-mean)*inv*lng2[dim] + lnb2[dim];
            hseq[(size_t)s*128 + dim] = ov;
            if (i < 8) o0[i] = (half_t)ov; else o1[i-8] = (half_t)ov;
        }
        *(half8*)swz_ptr(xt, token, part*16) = o0;
        *(half8*)swz_ptr(xt, token, part*16 + 8) = o1;
    } else {
        for (int c = tid; c < 512; c += 256) {
            int token = c >> 4, col8 = (c & 15) * 8;
            const float* src = hseq + (size_t)(s0 + token) * 128 + col8;
            float4 a = *(const float4*)src;
            float4 b = *(const float4*)(src + 4);
            half8 v;
            v[0]=(half_t)a.x; v[1]=(half_t)a.y; v[2]=(half_t)a.z; v[3]=(half_t)a.w;
            v[4]=(half_t)b.x; v[5]=(half_t)b.y; v[6]=(half_t)b.z; v[7]=(half_t)b.w;
            *(half8*)swz_ptr(xt, token, col8) = v;
        }
    }
    __syncthreads();
    int lane = tid & 63, w = tid >> 6;
    int lr = lane & 15, lg = lane >> 4;
    f32x4 acc[6][2];
    #pragma unroll
    for (int m = 0; m < 6; ++m)
        #pragma unroll
        for (int n = 0; n < 2; ++n) acc[m][n] = (f32x4){0.f, 0.f, 0.f, 0.f};
    #pragma unroll
    for (int ks = 0; ks < 4; ++ks) {
        half8 bf[2];
        #pragma unroll
        for (int n = 0; n < 2; ++n)
            bf[n] = *(half8*)swz_ptr(xt, n*16 + lr, ks*32 + lg*8);
        #pragma unroll
        for (int m = 0; m < 6; ++m) {
            int row = w*96 + m*16 + lr;
            half8 af = *(const half8*)(WqkvT + (size_t)row*128 + ks*32 + lg*8);
            #pragma unroll
            for (int n = 0; n < 2; ++n) acc[m][n] = MFMA16(af, bf[n], acc[m][n]);
        }
    }
    #pragma unroll
    for (int m = 0; m < 6; ++m) {
        int qd = w*96 + m*16 + lg*4;
        float4 bb = *(const float4*)(bqkv + qd);
        int part = qd >> 7, c = qd & 127, head = c >> 4, dd = c & 15;
        #pragma unroll
        for (int n = 0; n < 2; ++n) {
            int token = n*16 + lr;
            float v0 = acc[m][n][0] + bb.x, v1 = acc[m][n][1] + bb.y;
            float v2 = acc[m][n][2] + bb.z, v3 = acc[m][n][3] + bb.w;
            if (part == 0) {
                half4 hv = { (half_t)(v0*QSCALE), (half_t)(v1*QSCALE),
                             (half_t)(v2*QSCALE), (half_t)(v3*QSCALE) };
                *(half4*)(Qh + ((size_t)head*S + s0 + token)*HD + dd) = hv;
            } else if (part == 1) {
                half4 hv = { (half_t)v0, (half_t)v1, (half_t)v2, (half_t)v3 };
                *(half4*)(Kh + ((size_t)head*S + s0 + token)*HD + dd) = hv;
            } else {
                Vt[((size_t)head*HD + dd + 0)*S + s0 + token] = (half_t)v0;
                Vt[((size_t)head*HD + dd + 1)*S + s0 + token] = (half_t)v1;
                Vt[((size_t)head*HD + dd + 2)*S + s0 + token] = (half_t)v2;
                Vt[((size_t)head*HD + dd + 3)*S + s0 + token] = (half_t)v3;
            }
        }
    }
}

// ---------------- Attention v7: 32 queries/wave (128/block), 128-key LDS tiles ----------------
__global__ __launch_bounds__(256) void attn7_kernel(
        const half_t* __restrict__ Qh, const half_t* __restrict__ Kh,
        const half_t* __restrict__ Vt, float* __restrict__ pacc,
        float* __restrict__ pl) {
    int qb = blockIdx.x, h = blockIdx.y, ks = blockIdx.z;
    int tid = threadIdx.x;
    int lane = tid & 63;
    int w = tid >> 6;
    int lr = lane & 15, lg = lane >> 4;
    int qg0 = qb*128 + w*32 + lr;
    int qg1 = qg0 + 16;
    const f32x4 zf = {0.f, 0.f, 0.f, 0.f};

    __shared__ half_t kbuf[2][128*16];
    __shared__ half_t vbuf[2][16*VPAD2];

    half4 qf0 = *(const half4*)(Qh + ((size_t)h*S + qg0)*HD + lg*4);
    half4 qf1 = *(const half4*)(Qh + ((size_t)h*S + qg1)*HD + lg*4);

    int krow = tid >> 1, kch = tid & 1;
    int vdim = tid >> 4, vch = tid & 15;
    const half_t* Kbase = Kh + (size_t)h*S*HD;
    const half_t* Vbase = Vt + (size_t)h*HD*S;
    int kb0 = ks*(S/KS);

    *(half8*)&kbuf[0][krow*16 + kch*8] = *(const half8*)(Kbase + (size_t)(kb0+krow)*HD + kch*8);
    *(half8*)&vbuf[0][vdim*VPAD2 + vch*8] = *(const half8*)(Vbase + (size_t)vdim*S + kb0 + vch*8);
    __syncthreads();

    float l0 = 0.f, l1 = 0.f;
    f32x4 oa0 = zf, oa1 = zf, ob0 = zf, ob1 = zf;
    int cur = 0;
    const int NT = (S/KS)/128;               // 6
    for (int t = 0; t < NT; ++t) {
        half8 knext, vnext;
        if (t+1 < NT) {
            int kbn = kb0 + (t+1)*128;
            knext = *(const half8*)(Kbase + (size_t)(kbn+krow)*HD + kch*8);
            vnext = *(const half8*)(Vbase + (size_t)vdim*S + kbn + vch*8);
        }

        f32x4 sc0[8], sc1[8];
        #pragma unroll
        for (int ct = 0; ct < 8; ++ct) {
            half4 kf = *(half4*)&kbuf[cur][(ct*16+lr)*16 + lg*4];
            sc0[ct] = MFMA16K16(kf, qf0, zf);
            sc1[ct] = MFMA16K16(kf, qf1, zf);
        }
        half4 pf0[8], pf1[8];
        #pragma unroll
        for (int ct = 0; ct < 8; ++ct)
            #pragma unroll
            for (int r = 0; r < 4; ++r) {
                float pv0 = exp2f(sc0[ct][r] - SM_SHIFT2);
                float pv1 = exp2f(sc1[ct][r] - SM_SHIFT2);
                l0 += pv0; l1 += pv1;
                pf0[ct][r] = (half_t)pv0;
                pf1[ct][r] = (half_t)pv1;
            }
        #pragma unroll
        for (int ct = 0; ct < 8; ++ct) {
            half4 vf = *(half4*)&vbuf[cur][lr*VPAD2 + ct*16 + lg*4];
            if (ct & 1) { oa1 = MFMA16K16(vf, pf0[ct], oa1); ob1 = MFMA16K16(vf, pf1[ct], ob1); }
            else        { oa0 = MFMA16K16(vf, pf0[ct], oa0); ob0 = MFMA16K16(vf, pf1[ct], ob0); }
        }
        if (t+1 < NT) {
            *(half8*)&kbuf[cur^1][krow*16 + kch*8] = knext;
            *(half8*)&vbuf[cur^1][vdim*VPAD2 + vch*8] = vnext;
            __syncthreads();
            cur ^= 1;
        }
    }
    oa0[0]+=oa1[0]; oa0[1]+=oa1[1]; oa0[2]+=oa1[2]; oa0[3]+=oa1[3];
    ob0[0]+=ob1[0]; ob0[1]+=ob1[1]; ob0[2]+=ob1[2]; ob0[3]+=ob1[3];

    l0 += __shfl_xor(l0, 16, 64); l0 += __shfl_xor(l0, 32, 64);
    l1 += __shfl_xor(l1, 16, 64); l1 += __shfl_xor(l1, 32, 64);

    size_t oi0 = ((size_t)(ks*H + h) * S + qg0);
    size_t oi1 = ((size_t)(ks*H + h) * S + qg1);
    if (lg == 0) { pl[oi0] = l0; pl[oi1] = l1; }
    #pragma unroll
    for (int r = 0; r < 4; ++r) {
        pacc[oi0 * HD + lg*4 + r] = oa0[r];
        pacc[oi1 * HD + lg*4 + r] = ob0[r];
    }
}

// ---------------- out-proj + residual + LN via MFMA (32 tokens/block), attn-combine fused ----------------
__global__ __launch_bounds__(256) void oproj_mfma_ln_kernel(
        const float* __restrict__ pacc, const float* __restrict__ pl,
        const half_t* __restrict__ WoT,
        const float* __restrict__ bo, const float* __restrict__ lng,
        const float* __restrict__ lnb, float* __restrict__ hseq) {
    __shared__ half_t xt[32*128];
    __shared__ float yt[32*132];
    int tid = threadIdx.x;
    int s0 = blockIdx.x * 32;
    for (int c = tid; c < 512; c += 256) {
        int token = c >> 4, col8 = (c & 15) * 8;
        int s = s0 + token;
        int h = col8 >> 4, dd0 = col8 & 15;
        float L = 0.f;
        float a[8] = {0,0,0,0,0,0,0,0};
        #pragma unroll
        for (int k = 0; k < KS; ++k) {
            size_t oi = ((size_t)(k*H + h) * S + s);
            L += pl[oi];
            const float* pp = pacc + oi * HD + dd0;
            float4 p0 = *(const float4*)pp;
            float4 p1 = *(const float4*)(pp + 4);
            a[0]+=p0.x; a[1]+=p0.y; a[2]+=p0.z; a[3]+=p0.w;
            a[4]+=p1.x; a[5]+=p1.y; a[6]+=p1.z; a[7]+=p1.w;
        }
        float inv = 1.f / L;
        half8 v;
        #pragma unroll
        for (int i = 0; i < 8; ++i) v[i] = (half_t)(a[i] * inv);
        *(half8*)swz_ptr(xt, token, col8) = v;
    }
    __syncthreads();
    int lane = tid & 63, w = tid >> 6;
    int lr = lane & 15, lg = lane >> 4;
    f32x4 acc[2][2];
    #pragma unroll
    for (int m = 0; m < 2; ++m)
        #pragma unroll
        for (int n = 0; n < 2; ++n) acc[m][n] = (f32x4){0.f, 0.f, 0.f, 0.f};
    #pragma unroll
    for (int kk = 0; kk < 4; ++kk) {
        half8 bf[2];
        #pragma unroll
        for (int n = 0; n < 2; ++n)
            bf[n] = *(half8*)swz_ptr(xt, n*16 + lr, kk*32 + lg*8);
        #pragma unroll
        for (int m = 0; m < 2; ++m) {
            int row = w*32 + m*16 + lr;
            half8 af = *(const half8*)(WoT + (size_t)row*128 + kk*32 + lg*8);
            #pragma unroll
            for (int n = 0; n < 2; ++n) acc[m][n] = MFMA16(af, bf[n], acc[m][n]);
        }
    }
    #pragma unroll
    for (int m = 0; m < 2; ++m)
        #pragma unroll
        for (int n = 0; n < 2; ++n) {
            int token = n*16 + lr;
            int od = w*32 + m*16 + lg*4;
            *(f32x4*)&yt[token*132 + od] = acc[m][n];
        }
    __syncthreads();
    {
        int token = tid >> 3, part = tid & 7;
        const float* hres = hseq + (size_t)(s0 + token) * 128;
        float v[16];
        float sum = 0.f;
        #pragma unroll
        for (int i = 0; i < 16; ++i) {
            int dim = part*16 + i;
            v[i] = yt[token*132 + dim] + bo[dim] + hres[dim];
            sum += v[i];
        }
        sum += __shfl_xor(sum, 1, 64); sum += __shfl_xor(sum, 2, 64); sum += __shfl_xor(sum, 4, 64);
        float mean = sum * (1.f/128.f);
        float vs = 0.f;
        #pragma unroll
        for (int i = 0; i < 16; ++i) { float dq = v[i] - mean; vs += dq*dq; }
        vs += __shfl_xor(vs, 1, 64); vs += __shfl_xor(vs, 2, 64); vs += __shfl_xor(vs, 4, 64);
        float inv = rsqrtf(vs * (1.f/128.f) + 1e-5f);
        #pragma unroll
        for (int i = 0; i < 16; ++i) {
            int dim = part*16 + i;
            hseq[(size_t)(s0+token)*128 + dim] = (v[i]-mean)*inv*lng[dim] + lnb[dim];
        }
    }
}

// ---------------- FFN split-FF: grid (96, FCH) -> partial Y into ypart ----------------
__global__ __launch_bounds__(256) void ffn_mfma2_kernel(
        const half_t* __restrict__ W1T, const half_t* __restrict__ W2T,
        const float* __restrict__ b1, const float* __restrict__ hseq,
        float* __restrict__ ypart) {
    __shared__ half_t xt[32*128];      // 8 KB
    __shared__ half_t h1[32*256];      // 16 KB
    int tid = threadIdx.x;             // 256
    int s0 = blockIdx.x * 32;
    int fc = blockIdx.y;
    int fbase = fc * 256;
    for (int c = tid; c < 512; c += 256) {
        int token = c >> 4, col8 = (c & 15) * 8;
        const float* src = hseq + (size_t)(s0 + token) * 128 + col8;
        float4 a = *(const float4*)src;
        float4 b = *(const float4*)(src + 4);
        half8 v;
        v[0]=(half_t)a.x; v[1]=(half_t)a.y; v[2]=(half_t)a.z; v[3]=(half_t)a.w;
        v[4]=(half_t)b.x; v[5]=(half_t)b.y; v[6]=(half_t)b.z; v[7]=(half_t)b.w;
        *(half8*)swz_ptr(xt, token, col8) = v;
    }
    __syncthreads();
    int lane = tid & 63, mw = tid >> 6;
    int lr = lane & 15, lg = lane >> 4;

    f32x4 hacc[4][2];
    #pragma unroll
    for (int m = 0; m < 4; ++m)
        #pragma unroll
        for (int n = 0; n < 2; ++n) hacc[m][n] = (f32x4){0.f, 0.f, 0.f, 0.f};
    #pragma unroll
    for (int ksx = 0; ksx < 4; ++ksx) {
        half8 bf[2];
        #pragma unroll
        for (int n = 0; n < 2; ++n)
            bf[n] = *(half8*)swz_ptr(xt, n*16 + lr, ksx*32 + lg*8);
        #pragma unroll
        for (int m = 0; m < 4; ++m) {
            int row = fbase + mw*64 + m*16 + lr;
            half8 af = *(const half8*)(W1T + (size_t)row*128 + ksx*32 + lg*8);
            #pragma unroll
            for (int n = 0; n < 2; ++n) hacc[m][n] = MFMA16(af, bf[n], hacc[m][n]);
        }
    }
    #pragma unroll
    for (int m = 0; m < 4; ++m) {
        int frow = mw*64 + m*16 + lg*4;
        float4 bb = *(const float4*)(b1 + fbase + frow);
        #pragma unroll
        for (int n = 0; n < 2; ++n) {
            int token = n*16 + lr;
            half4 hv;
            hv[0] = (half_t)fmaxf(hacc[m][n][0] + bb.x, 0.f);
            hv[1] = (half_t)fmaxf(hacc[m][n][1] + bb.y, 0.f);
            hv[2] = (half_t)fmaxf(hacc[m][n][2] + bb.z, 0.f);
            hv[3] = (half_t)fmaxf(hacc[m][n][3] + bb.w, 0.f);
            *(half4*)swz_ptr256(h1, token, frow) = hv;
        }
    }
    __syncthreads();

    f32x4 yacc[2][2];
    #pragma unroll
    for (int m = 0; m < 2; ++m)
        #pragma unroll
        for (int n = 0; n < 2; ++n) yacc[m][n] = (f32x4){0.f, 0.f, 0.f, 0.f};
    #pragma unroll
    for (int ksx = 0; ksx < 8; ++ksx) {
        half8 bf[2];
        #pragma unroll
        for (int n = 0; n < 2; ++n)
            bf[n] = *(half8*)swz_ptr256(h1, n*16 + lr, ksx*32 + lg*8);
        #pragma unroll
        for (int m = 0; m < 2; ++m) {
            int row = mw*32 + m*16 + lr;
            half8 af = *(const half8*)(W2T + (size_t)row*2048 + fbase + ksx*32 + lg*8);
            #pragma unroll
            for (int n = 0; n < 2; ++n) yacc[m][n] = MFMA16(af, bf[n], yacc[m][n]);
        }
    }
    #pragma unroll
    for (int m = 0; m < 2; ++m)
        #pragma unroll
        for (int n = 0; n < 2; ++n) {
            int token = n*16 + lr;
            int od = mw*32 + m*16 + lg*4;
            *(f32x4*)&ypart[((size_t)fc*S + s0 + token)*128 + od] = yacc[m][n];
        }
}

// ---------------- FFN reduce + bias + residual + LN (last layer) + pool partials ----------------
__global__ __launch_bounds__(256) void ffn_reduce_ln_pool_kernel(
        const float* __restrict__ ypart, const float* __restrict__ b2,
        const float* __restrict__ lng, const float* __restrict__ lnb,
        float* __restrict__ hseq, float* __restrict__ gpart) {
    __shared__ float wsum[4][128];
    int tid = threadIdx.x;             // 256: 64 tokens x 4 parts
    int token = blockIdx.x * 64 + (tid >> 2);
    int part = tid & 3;                // 32 dims each
    int lane = tid & 63, wv = tid >> 6;
    const float* hres = hseq + (size_t)token * 128;
    float v[32];
    #pragma unroll
    for (int i = 0; i < 32; ++i) {
        int dim = part*32 + i;
        v[i] = b2[dim] + hres[dim];
    }
    #pragma unroll
    for (int fcc = 0; fcc < FCH; ++fcc) {
        const float* yp = ypart + ((size_t)fcc*S + token)*128 + part*32;
        #pragma unroll
        for (int i = 0; i < 32; ++i) v[i] += yp[i];
    }
    float sum = 0.f;
    #pragma unroll
    for (int i = 0; i < 32; ++i) sum += v[i];
    sum += __shfl_xor(sum, 1, 64); sum += __shfl_xor(sum, 2, 64);
    float mean = sum * (1.f/128.f);
    float vs = 0.f;
    #pragma unroll
    for (int i = 0; i < 32; ++i) { float dq = v[i] - mean; vs += dq*dq; }
    vs += __shfl_xor(vs, 1, 64); vs += __shfl_xor(vs, 2, 64);
    float inv = rsqrtf(vs * (1.f/128.f) + 1e-5f);
    float o[32];
    #pragma unroll
    for (int i = 0; i < 32; ++i) {
        int dim = part*32 + i;
        o[i] = (v[i]-mean)*inv*lng[dim] + lnb[dim];
        hseq[(size_t)token*128 + dim] = o[i];
    }
    // pool partial: sum o[] across the 16 tokens of this wave
    #pragma unroll
    for (int i = 0; i < 32; ++i) {
        o[i] += __shfl_xor(o[i], 4, 64);
        o[i] += __shfl_xor(o[i], 8, 64);
        o[i] += __shfl_xor(o[i], 16, 64);
        o[i] += __shfl_xor(o[i], 32, 64);
    }
    if (lane < 4) {
        #pragma unroll
        for (int i = 0; i < 32; ++i) wsum[wv][lane*32 + i] = o[i];
    }
    __syncthreads();
    if (tid < 128)
        gpart[(size_t)blockIdx.x * 128 + tid] =
            wsum[0][tid] + wsum[1][tid] + wsum[2][tid] + wsum[3][tid];
}

// ---------------- heads (reduces pool partials first) ----------------
__global__ __launch_bounds__(128) void heads_kernel(
        const float* __restrict__ gpart,
        const float* __restrict__ rW1, const float* __restrict__ rb1,
        const float* __restrict__ rW2, const float* __restrict__ rb2,
        const float* __restrict__ mW1, const float* __restrict__ mb1,
        const float* __restrict__ mW2, const float* __restrict__ mb2,
        const float* __restrict__ uW1, const float* __restrict__ ub1,
        const float* __restrict__ uW2, const float* __restrict__ ub2,
        float* __restrict__ out) {
    int tid = threadIdx.x;           // 128
    __shared__ float gl[D];
    __shared__ float r1[64];
    __shared__ float mh[32];
    __shared__ float uh[32];
    {
        float acc = 0.f;
        for (int b = 0; b < NB; ++b) acc += gpart[(size_t)b * 128 + tid];
        gl[tid] = acc * (1.f / S);
    }
    __syncthreads();
    if (tid < 64) {
        float acc = rb1[tid];
        for (int k = 0; k < D; ++k) acc += gl[k] * rW1[k * 64 + tid];
        r1[tid] = fmaxf(acc, 0.f);
    }
    if (tid >= 64 && tid < 96) {
        int t = tid - 64;
        float am = mb1[t], au = ub1[t];
        for (int k = 0; k < D; ++k) {
            am += gl[k] * mW1[k * 32 + t];
            au += gl[k] * uW1[k * 32 + t];
        }
        mh[t] = fmaxf(am, 0.f);
        uh[t] = fmaxf(au, 0.f);
    }
    __syncthreads();
    if (tid == 0) {
        float acc = rb2[0];
        for (int k = 0; k < 64; ++k) acc += r1[k] * rW2[k];
        out[0] = 1.f / (1.f + __expf(-acc));
    }
    if (tid >= 8 && tid < 16) {
        int t = tid - 8;
        float acc = mb2[t];
        for (int k = 0; k < 32; ++k) acc += mh[k] * mW2[k * 8 + t];
        out[1 + t] = acc;
    }
    if (tid >= 16 && tid < 18) {
        int t = tid - 16;
        float acc = ub2[t];
        for (int k = 0; k < 32; ++k) acc += uh[k] * uW2[k * 2 + t];
        out[9 + t] = (acc > 20.f) ? acc : log1pf(__expf(acc));
    }
}

extern "C" void kernel_launch(void* const* d_in, const int* in_sizes, int n_in,
                              void* d_out, int out_size, void* d_ws, size_t ws_size,
                              hipStream_t stream) {
    const float* x       = (const float*)d_in[0];
    const int*   ei      = (const int*)  d_in[1];
    const float* gat_W   = (const float*)d_in[2];
    const float* gat_asrc= (const float*)d_in[3];
    const float* gat_adst= (const float*)d_in[4];
    const float* gat_b   = (const float*)d_in[5];
    const float* ln_g    = (const float*)d_in[6];
    const float* ln_b    = (const float*)d_in[7];
    const float* Wqkv    = (const float*)d_in[8];
    const float* bqkv    = (const float*)d_in[9];
    const float* Wo      = (const float*)d_in[10];
    const float* bo      = (const float*)d_in[11];
    const float* ln1g    = (const float*)d_in[12];
    const float* ln1b    = (const float*)d_in[13];
    const float* W1      = (const float*)d_in[14];
    const float* b1      = (const float*)d_in[15];
    const float* W2      = (const float*)d_in[16];
    const float* b2      = (const float*)d_in[17];
    const float* ln2g    = (const float*)d_in[18];
    const float* ln2b    = (const float*)d_in[19];
    const float* rW1     = (const float*)d_in[20];
    const float* rb1     = (const float*)d_in[21];
    const float* rW2     = (const float*)d_in[22];
    const float* rb2     = (const float*)d_in[23];
    const float* mW1     = (const float*)d_in[24];
    const float* mb1     = (const float*)d_in[25];
    const float* mW2     = (const float*)d_in[26];
    const float* mb2     = (const float*)d_in[27];
    const float* uW1     = (const float*)d_in[28];
    const float* ub1     = (const float*)d_in[29];
    const float* uW2     = (const float*)d_in[30];
    const float* ub2     = (const float*)d_in[31];

    float* ws = (float*)d_ws;
    half_t*       hbuf16 = (half_t*)(ws + O_A);
    half_t*       Qh   = (half_t*)(ws + O_A);
    half_t*       Kh   = Qh + (size_t)H*S*HD;
    half_t*       Vt   = Kh + (size_t)H*S*HD;
    half_t*       wb   = (half_t*)(ws + O_A + WB_OFF);
    half_t*       WqkvT= wb + WB_QKV;
    half_t*       WoT  = wb + WB_WO;
    half_t*       W1T  = wb + WB_W1;
    half_t*       W2T  = wb + WB_W2;
    float*        pacc = ws + O_C;
    float*        ypart= ws + O_C;
    float*        pl   = ws + O_C + (size_t)KS*H*S*HD;
    float*        hseq = ws + O_HSEQ;
    float*        ssrc = ws + O_SSRC;
    float*        sdst = ws + O_SDST;
    int*          ia   = (int*)(ws + O_INT);
    float*        gpart= ws + O_G;
    float* out = (float*)d_out;

    // ---- GAT ----
    gat_lin_kernel<<<dim3(T*N), dim3(256), 0, stream>>>(x, gat_W, gat_asrc, gat_adst,
                                                        hbuf16, ssrc, sdst);
    csr_build_kernel<<<dim3(1), dim3(512), 0, stream>>>(ei, ia);
    gat_fused_kernel<<<dim3(T*N), dim3(128), 0, stream>>>(
        ei, ia, ssrc, sdst, hbuf16, gat_b, ln_g, ln_b, hseq);

    // ---- weight convert ----
    wconv_kernel<<<dim3(3*576), dim3(256), 0, stream>>>(Wqkv, Wo, W1, W2, WqkvT, WoT, W1T, W2T);

    // ---- transformer layers ----
    for (int l = 0; l < 3; ++l) {
        qkv_mfma_kernel<<<dim3(S/32), dim3(256), 0, stream>>>(
            hseq, ypart, b2 + (l-1)*D, ln2g + (l-1)*D, ln2b + (l-1)*D, (l > 0) ? 1 : 0,
            WqkvT + (size_t)l*384*128, bqkv + l*3*D, Qh, Kh, Vt);
        attn7_kernel<<<dim3(S/128, H, KS), dim3(256), 0, stream>>>(Qh, Kh, Vt, pacc, pl);
        oproj_mfma_ln_kernel<<<dim3(S/32), dim3(256), 0, stream>>>(
            pacc, pl, WoT + (size_t)l*128*128, bo + l*D, ln1g + l*D, ln1b + l*D, hseq);
        ffn_mfma2_kernel<<<dim3(S/32, FCH), dim3(256), 0, stream>>>(
            W1T + (size_t)l*2048*128, W2T + (size_t)l*128*2048,
            b1 + l*FF, hseq, ypart);
    }
    // last layer's FFN reduce + LN + pool partials
    ffn_reduce_ln_pool_kernel<<<dim3(NB), dim3(256), 0, stream>>>(
        ypart, b2 + 2*D, ln2g + 2*D, ln2b + 2*D, hseq, gpart);

    // ---- heads ----
    heads_kernel<<<dim3(1), dim3(128), 0, stream>>>(gpart, rW1, rb1, rW2, rb2,
                                                    mW1, mb1, mW2, mb2,
                                                    uW1, ub1, uW2, ub2, out);
}